// Round 4
// baseline (901.638 us; speedup 1.0000x reference)
//
#include <hip/hip_runtime.h>
#include <hip/hip_bf16.h>

// ---------------- problem constants ----------------
#define CEMB 256
#define NHEAD 8
#define DHEAD 32
#define DFF 1024
#define BB 4
#define HH 128
#define WW 128
#define WSZ 16
#define NWH 8
#define NW 64
#define TT 256            // tokens per window
#define NTOK (BB*NW*TT)   // 65536

typedef __attribute__((ext_vector_type(8))) short bf16x8;
typedef __attribute__((ext_vector_type(4))) float f32x4;

// bf16 helpers (storage type = ushort)
__device__ __forceinline__ float bf2f(unsigned short u){
    union { float f; unsigned int i; } v; v.i = ((unsigned int)u) << 16; return v.f;
}
__device__ __forceinline__ unsigned short f2bf(float f){
    union { float f; unsigned int i; } v; v.f = f;
    unsigned int r = v.i + 0x7fffu + ((v.i >> 16) & 1u);
    return (unsigned short)(r >> 16);
}
__device__ __forceinline__ unsigned int cvtpk_bf16(float lo, float hi){
    unsigned int r;
    asm("v_cvt_pk_bf16_f32 %0, %1, %2" : "=v"(r) : "v"(lo), "v"(hi));
    return r;
}
__device__ __forceinline__ void unpack8(uint4 v, float* f){
    f[0]=bf2f((unsigned short)(v.x & 0xffff)); f[1]=bf2f((unsigned short)(v.x>>16));
    f[2]=bf2f((unsigned short)(v.y & 0xffff)); f[3]=bf2f((unsigned short)(v.y>>16));
    f[4]=bf2f((unsigned short)(v.z & 0xffff)); f[5]=bf2f((unsigned short)(v.z>>16));
    f[6]=bf2f((unsigned short)(v.w & 0xffff)); f[7]=bf2f((unsigned short)(v.w>>16));
}
__device__ __forceinline__ void async_copy16(const void* g, void* l){
    __builtin_amdgcn_global_load_lds(
        (const __attribute__((address_space(1))) unsigned int*)g,
        (__attribute__((address_space(3))) unsigned int*)l, 16, 0, 0);
}
// xor-swizzled LDS granule index for 64c x 128t fp32 transpose tiles
// (granule = 4 floats along t; phys granule = c*32 + (g ^ (c&31)))
__device__ __forceinline__ int sgran(int c, int g){ return c*32 + (g ^ (c & 31)); }

// ---------------- rel MLP: rel[t][c] fp32 (once) ----------------
__global__ __launch_bounds__(256) void rel_kernel(const float* __restrict__ rw1,
    const float* __restrict__ rb1, const float* __restrict__ rw2,
    const float* __restrict__ rb2, float* __restrict__ rel)
{
    __shared__ float hsh[64];
    int t = blockIdx.x, c = threadIdx.x;
    int ty = t >> 4, tx = t & 15;
    if (c < 64){
        float y = ty*(1.0f/15.0f), xx = tx*(1.0f/15.0f);
        hsh[c] = fmaxf(y*rw1[2*c] + xx*rw1[2*c+1] + rb1[c], 0.0f);
    }
    __syncthreads();
    float acc = rb2[c];
    #pragma unroll 16
    for (int k = 0; k < 64; ++k) acc += hsh[k]*rw2[c*64 + k];
    rel[t*256 + c] = acc;
}

// ---------------- pos[w][t][c] = gp^T + rel  (vectorized swizzled transpose) ----------------
// grid: 64 w * 4 cq * 2 th = 512 blocks; 64 c x 128 t tile per block
__global__ __launch_bounds__(256) void posT_kernel(const float* __restrict__ gp,
    const float* __restrict__ rel, unsigned short* __restrict__ pos)
{
    __shared__ float tile[8192];
    const int w  = blockIdx.x >> 3;
    const int cq = (blockIdx.x >> 1) & 3, th = blockIdx.x & 1;
    const int c0 = cq << 6, t0 = th << 7, y0 = th << 3;
    const int wh = w >> 3, wwi = w & 7;
    const int tid = threadIdx.x;
    const float* gpb = gp + (size_t)c0*(HH*WW) + (size_t)(wh*16 + y0)*WW + wwi*16;
    #pragma unroll
    for (int i = 0; i < 8; ++i){
        int n = i*256 + tid, slot = n & 31, c = n >> 5;
        int yl = slot >> 2, xg = slot & 3;
        float4 v = *(const float4*)(gpb + (size_t)c*(HH*WW) + yl*WW + xg*4);
        *(float4*)&tile[sgran(c, slot)*4] = v;
    }
    __syncthreads();
    #pragma unroll
    for (int i = 0; i < 4; ++i){
        int n = i*256 + tid, j = n & 7, tl = n >> 3;
        int g = tl >> 2, e = tl & 3;
        const float* rl = rel + (t0 + tl)*256 + c0 + j*8;
        unsigned short o[8];
        #pragma unroll
        for (int m = 0; m < 8; ++m)
            o[m] = f2bf(tile[sgran(j*8 + m, g)*4 + e] + rl[m]);
        *(uint4*)&pos[((size_t)w*256 + t0 + tl)*CEMB + c0 + j*8] = *(uint4*)o;
    }
}

// ---------------- K2: window validity (max-pool > 0) ----------------
__global__ __launch_bounds__(256) void valid_kernel(const float* __restrict__ defe,
    float* __restrict__ validf, float* __restrict__ tail)
{
    __shared__ float red[4];
    int bw = blockIdx.x; int b = bw >> 6, w = bw & 63;
    int t = threadIdx.x; int ty = t >> 4, tx = t & 15;
    int wh = w >> 3, wwi = w & 7;
    float v = defe[(size_t)b*(HH*WW) + (wh*16+ty)*WW + wwi*16 + tx];
    int lane = t & 63, wave = t >> 6;
    for (int off = 1; off < 64; off <<= 1) v = fmaxf(v, __shfl_xor(v, off));
    if (lane == 0) red[wave] = v;
    __syncthreads();
    if (t == 0){
        float m = fmaxf(fmaxf(red[0], red[1]), fmaxf(red[2], red[3]));
        float r = (m > 0.0f) ? 1.0f : 0.0f;
        validf[bw] = r;
        tail[bw] = r;
    }
}

// ---------------- K3: window partition  backbone[B,C,H,W] -> x[b,w,t,c] bf16 ----------------
// grid: 256 bw * 4 cq * 2 th = 2048 blocks; 64 c x 128 t tile per block
__global__ __launch_bounds__(256) void partition_kernel(const float* __restrict__ bb,
    unsigned short* __restrict__ x)
{
    __shared__ float tile[8192];
    const int bw = blockIdx.x >> 3;
    const int b = bw >> 6, w = bw & 63;
    const int cq = (blockIdx.x >> 1) & 3, th = blockIdx.x & 1;
    const int c0 = cq << 6, t0 = th << 7, y0 = th << 3;
    const int wh = w >> 3, wwi = w & 7;
    const int tid = threadIdx.x;
    const float* bbb = bb + ((size_t)(b*CEMB + c0))*(HH*WW) + (size_t)(wh*16 + y0)*WW + wwi*16;
    #pragma unroll
    for (int i = 0; i < 8; ++i){
        int n = i*256 + tid, slot = n & 31, c = n >> 5;
        int yl = slot >> 2, xg = slot & 3;
        float4 v = *(const float4*)(bbb + (size_t)c*(HH*WW) + yl*WW + xg*4);
        *(float4*)&tile[sgran(c, slot)*4] = v;
    }
    __syncthreads();
    #pragma unroll
    for (int i = 0; i < 4; ++i){
        int n = i*256 + tid, j = n & 7, tl = n >> 3;
        int g = tl >> 2, e = tl & 3;
        unsigned short o[8];
        #pragma unroll
        for (int m = 0; m < 8; ++m)
            o[m] = f2bf(tile[sgran(j*8 + m, g)*4 + e]);
        *(uint4*)&x[((size_t)bw*256 + t0 + tl)*CEMB + c0 + j*8] = *(uint4*)o;
    }
}

// ---------------- weight fp32 -> bf16 ----------------
__global__ __launch_bounds__(256) void wcvt_kernel(const float* __restrict__ w,
    unsigned short* __restrict__ o, int n4)
{
    int i = blockIdx.x*256 + threadIdx.x;
    if (i < n4){
        float4 v = ((const float4*)w)[i];
        ushort4 u;
        u.x = f2bf(v.x); u.y = f2bf(v.y); u.z = f2bf(v.z); u.w = f2bf(v.w);
        ((ushort4*)o)[i] = u;
    }
}

// ---------------- xp = x + pos (bf16 elementwise, 8 el/thread) ----------------
__global__ __launch_bounds__(256) void addpos_kernel(const unsigned short* __restrict__ x,
    const unsigned short* __restrict__ pos, unsigned short* __restrict__ xp)
{
    size_t i = ((size_t)blockIdx.x*256 + threadIdx.x) * 8;
    size_t tok = i >> 8; int c = (int)(i & 255);
    size_t pi = ((tok & 16383) << 8) + c;
    uint4 xv = *(const uint4*)&x[i];
    uint4 pv = *(const uint4*)&pos[pi];
    float xf[8], pf[8]; unpack8(xv, xf); unpack8(pv, pf);
    unsigned short o[8];
    #pragma unroll
    for (int j = 0; j < 8; ++j) o[j] = f2bf(xf[j] + pf[j]);
    *(uint4*)&xp[i] = *(uint4*)o;
}

// ---------------- MFMA GEMM: out[M,N](bf16) = A[M,K](bf16) @ W[N,K]^T + bias ----------------
// K-tile LDS layout is XOR-swizzled at 16B granule: phys granule (r, g) holds
// logical granule (r, g ^ ((r>>1)&3)).  global_load_lds writes linearly, so the
// swizzle is applied by pre-swizzling the *source* offset; reads XOR the granule.
__global__ __launch_bounds__(256) void gemm_mfma(
    const unsigned short* __restrict__ A,
    const unsigned short* __restrict__ A2, int nsplit, int ldA,
    const unsigned short* __restrict__ W, int K,
    const float* __restrict__ bias,
    unsigned short* __restrict__ out, int ldO, int relu)
{
    __shared__ unsigned short As[128*32];
    __shared__ unsigned short Bs[128*32];
    const int m0 = blockIdx.x << 7, n0 = blockIdx.y << 7;
    const int tid = threadIdx.x;
    const int lane = tid & 63, wave = tid >> 6;
    const int wm = wave & 1, wn = wave >> 1;
    const int fl = lane & 15, quad = lane >> 4;

    const unsigned short* Ap = ((n0 < nsplit) ? A : A2) + (size_t)m0*ldA;
    const unsigned short* Wp = W + (size_t)n0*K;

    const int c0 = tid, c1 = tid + 256;
    const int r0 = c0 >> 2, o0 = ((c0 & 3) ^ ((c0 >> 3) & 3)) << 3;
    const int r1 = c1 >> 2, o1 = ((c1 & 3) ^ ((c1 >> 3) & 3)) << 3;
    // read-side swizzle: row bits 1..2 == fl bits 1..2 (i*16, wm*64 don't touch them)
    const int sw = (quad ^ ((fl >> 1) & 3)) << 3;

    f32x4 acc[4][4] = {};

    for (int k0 = 0; k0 < K; k0 += 32){
        async_copy16(Ap + (size_t)r0*ldA + k0 + o0, &As[c0 << 3]);
        async_copy16(Ap + (size_t)r1*ldA + k0 + o1, &As[c1 << 3]);
        async_copy16(Wp + (size_t)r0*K   + k0 + o0, &Bs[c0 << 3]);
        async_copy16(Wp + (size_t)r1*K   + k0 + o1, &Bs[c1 << 3]);
        __syncthreads();
        bf16x8 av[4], bv[4];
        #pragma unroll
        for (int i = 0; i < 4; ++i){
            av[i] = *(const bf16x8*)&As[(wm*64 + i*16 + fl)*32 + sw];
            bv[i] = *(const bf16x8*)&Bs[(wn*64 + i*16 + fl)*32 + sw];
        }
        #pragma unroll
        for (int i = 0; i < 4; ++i)
            #pragma unroll
            for (int j = 0; j < 4; ++j)
                acc[i][j] = __builtin_amdgcn_mfma_f32_16x16x32_bf16(av[i], bv[j], acc[i][j], 0, 0, 0);
        __syncthreads();
    }

    float bj[4];
    #pragma unroll
    for (int j = 0; j < 4; ++j) bj[j] = bias[n0 + wn*64 + j*16 + fl];
    #pragma unroll
    for (int i = 0; i < 4; ++i){
        int mrow = m0 + wm*64 + i*16 + quad*4;
        #pragma unroll
        for (int j = 0; j < 4; ++j){
            int col = n0 + wn*64 + j*16 + fl;
            #pragma unroll
            for (int r = 0; r < 4; ++r){
                float v = acc[i][j][r] + bj[j];
                if (relu) v = fmaxf(v, 0.0f);
                out[(size_t)(mrow + r)*ldO + col] = f2bf(v);
            }
        }
    }
}

// ---------------- MFMA GEMM + residual + LayerNorm (N == 256 exactly) ----------------
// 64-row tile, 4 waves each owning a 64x64 quadrant of columns: acc = 64 f32/lane
__global__ __launch_bounds__(256, 3) void gemm_ln(
    const unsigned short* __restrict__ A, int K,
    const unsigned short* __restrict__ W,
    const float* __restrict__ bias,
    const unsigned short* __restrict__ resid,
    const float* __restrict__ g, const float* __restrict__ b,
    unsigned short* __restrict__ out)
{
    __shared__ unsigned short As[64*32];
    __shared__ unsigned short Bs[256*32];
    __shared__ float psum[4][64];
    __shared__ float psq[4][64];
    const int m0 = blockIdx.x << 6;
    const int tid = threadIdx.x, lane = tid & 63, wave = tid >> 6;
    const int wn = wave;
    const int fl = lane & 15, quad = lane >> 4;

    const unsigned short* Ap = A + (size_t)m0*K;

    const int ra = tid >> 2, oa = ((tid & 3) ^ ((tid >> 3) & 3)) << 3;
    const int sw = (quad ^ ((fl >> 1) & 3)) << 3;

    f32x4 acc[4][4] = {};

    for (int k0 = 0; k0 < K; k0 += 32){
        async_copy16(Ap + (size_t)ra*K + k0 + oa, &As[tid << 3]);
        #pragma unroll
        for (int t = 0; t < 4; ++t){
            int c = tid + t*256;
            int r = c >> 2, o = ((c & 3) ^ ((c >> 3) & 3)) << 3;
            async_copy16(W + (size_t)r*K + k0 + o, &Bs[c << 3]);
        }
        __syncthreads();
        bf16x8 av[4], bv[4];
        #pragma unroll
        for (int i = 0; i < 4; ++i)
            av[i] = *(const bf16x8*)&As[(i*16 + fl)*32 + sw];
        #pragma unroll
        for (int j = 0; j < 4; ++j)
            bv[j] = *(const bf16x8*)&Bs[(wn*64 + j*16 + fl)*32 + sw];
        #pragma unroll
        for (int i = 0; i < 4; ++i)
            #pragma unroll
            for (int j = 0; j < 4; ++j)
                acc[i][j] = __builtin_amdgcn_mfma_f32_16x16x32_bf16(av[i], bv[j], acc[i][j], 0, 0, 0);
        __syncthreads();
    }

    float bcol[4], gcol[4], bbcol[4];
    #pragma unroll
    for (int j = 0; j < 4; ++j){
        int col = wn*64 + j*16 + fl;
        bcol[j] = bias[col]; gcol[j] = g[col]; bbcol[j] = b[col];
    }
    float s[4][4] = {{0}}, sq[4][4] = {{0}};
    #pragma unroll
    for (int i = 0; i < 4; ++i)
        #pragma unroll
        for (int r = 0; r < 4; ++r){
            int row = m0 + i*16 + quad*4 + r;
            #pragma unroll
            for (int j = 0; j < 4; ++j){
                float h = acc[i][j][r] + bcol[j]
                        + bf2f(resid[(size_t)row*256 + wn*64 + j*16 + fl]);
                acc[i][j][r] = h;
                s[i][r] += h; sq[i][r] += h*h;
            }
        }
    #pragma unroll
    for (int i = 0; i < 4; ++i)
        #pragma unroll
        for (int r = 0; r < 4; ++r){
            float ss = s[i][r], qq = sq[i][r];
            ss += __shfl_xor(ss, 1); qq += __shfl_xor(qq, 1);
            ss += __shfl_xor(ss, 2); qq += __shfl_xor(qq, 2);
            ss += __shfl_xor(ss, 4); qq += __shfl_xor(qq, 4);
            ss += __shfl_xor(ss, 8); qq += __shfl_xor(qq, 8);
            if (fl == 0){
                int lr = i*16 + quad*4 + r;
                psum[wn][lr] = ss; psq[wn][lr] = qq;
            }
        }
    __syncthreads();
    #pragma unroll
    for (int i = 0; i < 4; ++i)
        #pragma unroll
        for (int r = 0; r < 4; ++r){
            int lr = i*16 + quad*4 + r;
            float mu  = (psum[0][lr] + psum[1][lr] + psum[2][lr] + psum[3][lr]) * (1.0f/256.0f);
            float var = (psq[0][lr] + psq[1][lr] + psq[2][lr] + psq[3][lr]) * (1.0f/256.0f) - mu*mu;
            float rstd = rsqrtf(var + 1e-5f);
            #pragma unroll
            for (int j = 0; j < 4; ++j){
                int col = wn*64 + j*16 + fl;
                out[(size_t)(m0 + lr)*256 + col] =
                    f2bf((acc[i][j][r] - mu)*rstd*gcol[j] + bbcol[j]);
            }
        }
}

// ---------------- fused FFN: out = LN2( src + relu(src@W1^T+b1)@W2^T + b2 ) ----------------
// 64-row block, 4 waves. Hidden (1024) processed in 16 chunks of 64: GEMM1 uses
// the swapped-operand MFMA (h^T layout, like attention's S^T), relu+bias,
// cvt_pk -> bf16 into an XOR-swizzled 8KB LDS tile; GEMM2 accumulates into the
// standard C layout; epilogue = gemm_ln's residual+LN. Weights are register
// fragments read straight from L2 (1MB total, grid-wide reuse). src lives in
// 128 persistent VGPRs. ff intermediate never touches HBM.
__global__ __launch_bounds__(256) void ffn_fused(
    const unsigned short* __restrict__ src,
    const unsigned short* __restrict__ w1,   // [1024][256] bf16
    const float* __restrict__ b1,
    const unsigned short* __restrict__ w2,   // [256][1024] bf16
    const float* __restrict__ b2,
    const float* __restrict__ g, const float* __restrict__ b,
    unsigned short* __restrict__ out)
{
    __shared__ unsigned short hlds[64*64];   // [row][hid-chunk], 16B-granule XOR swizzle
    __shared__ float psum[4][64];
    __shared__ float psq[4][64];
    const int m0 = blockIdx.x << 6;
    const int tid = threadIdx.x, lane = tid & 63, wave = tid >> 6;
    const int fl = lane & 15, quad = lane >> 4;

    // persistent src fragments: qf[mi][kf] = src[m0+mi*16+fl][kf*32+quad*8 ..+8]
    bf16x8 qf[4][8];
    #pragma unroll
    for (int mi = 0; mi < 4; ++mi)
        #pragma unroll
        for (int kf = 0; kf < 8; ++kf)
            qf[mi][kf] = *(const bf16x8*)&src[(size_t)(m0 + mi*16 + fl)*256 + kf*32 + quad*8];

    f32x4 acc[4][4] = {};
    const int gwr = wave*2 + (quad >> 1);    // write-side h granule (8-ushort units)
    const int who = (quad & 1) << 2;         // within-granule ushort offset base

    for (int c = 0; c < 16; ++c){
        const int j0 = c << 6;
        // ---- GEMM1: h^T[16 hid (this wave)][64 rows] = W1c . src^T ----
        bf16x8 w1f[8];
        #pragma unroll
        for (int kf = 0; kf < 8; ++kf)
            w1f[kf] = *(const bf16x8*)&w1[(size_t)(j0 + wave*16 + fl)*256 + kf*32 + quad*8];
        float4 b1v = *(const float4*)&b1[j0 + wave*16 + quad*4];
        #pragma unroll
        for (int mi = 0; mi < 4; ++mi){
            f32x4 sacc = {};
            #pragma unroll
            for (int kf = 0; kf < 8; ++kf)
                sacc = __builtin_amdgcn_mfma_f32_16x16x32_bf16(w1f[kf], qf[mi][kf], sacc, 0, 0, 0);
            // lane holds h[hid = wave*16+quad*4+r][row = mi*16+fl]
            float h0 = fmaxf(sacc[0] + b1v.x, 0.0f);
            float h1 = fmaxf(sacc[1] + b1v.y, 0.0f);
            float h2 = fmaxf(sacc[2] + b1v.z, 0.0f);
            float h3 = fmaxf(sacc[3] + b1v.w, 0.0f);
            int r_ = mi*16 + fl;
            int gb = r_*64 + ((gwr ^ (fl & 7)) << 3) + who;
            *(unsigned int*)&hlds[gb    ] = cvtpk_bf16(h0, h1);
            *(unsigned int*)&hlds[gb + 2] = cvtpk_bf16(h2, h3);
        }
        __syncthreads();
        // ---- GEMM2: acc += h . W2c^T ----
        #pragma unroll
        for (int kk = 0; kk < 2; ++kk){
            bf16x8 hf[4], w2f[4];
            #pragma unroll
            for (int mi = 0; mi < 4; ++mi)
                hf[mi] = *(const bf16x8*)&hlds[(mi*16 + fl)*64 + (((kk*4 + quad) ^ (fl & 7)) << 3)];
            #pragma unroll
            for (int nd = 0; nd < 4; ++nd)
                w2f[nd] = *(const bf16x8*)&w2[(size_t)(wave*64 + nd*16 + fl)*1024 + j0 + kk*32 + quad*8];
            #pragma unroll
            for (int mi = 0; mi < 4; ++mi)
                #pragma unroll
                for (int nd = 0; nd < 4; ++nd)
                    acc[mi][nd] = __builtin_amdgcn_mfma_f32_16x16x32_bf16(hf[mi], w2f[nd], acc[mi][nd], 0, 0, 0);
        }
        __syncthreads();
    }

    // ---- epilogue: + b2 + resid(src), LayerNorm(g,b) -> out ----
    float bcol[4], gcol[4], bbcol[4];
    #pragma unroll
    for (int j = 0; j < 4; ++j){
        int col = wave*64 + j*16 + fl;
        bcol[j] = b2[col]; gcol[j] = g[col]; bbcol[j] = b[col];
    }
    float s[4][4] = {{0}}, sq[4][4] = {{0}};
    #pragma unroll
    for (int i = 0; i < 4; ++i)
        #pragma unroll
        for (int r = 0; r < 4; ++r){
            int row = m0 + i*16 + quad*4 + r;
            #pragma unroll
            for (int j = 0; j < 4; ++j){
                float h = acc[i][j][r] + bcol[j]
                        + bf2f(src[(size_t)row*256 + wave*64 + j*16 + fl]);
                acc[i][j][r] = h;
                s[i][r] += h; sq[i][r] += h*h;
            }
        }
    #pragma unroll
    for (int i = 0; i < 4; ++i)
        #pragma unroll
        for (int r = 0; r < 4; ++r){
            float ss = s[i][r], qq = sq[i][r];
            ss += __shfl_xor(ss, 1); qq += __shfl_xor(qq, 1);
            ss += __shfl_xor(ss, 2); qq += __shfl_xor(qq, 2);
            ss += __shfl_xor(ss, 4); qq += __shfl_xor(qq, 4);
            ss += __shfl_xor(ss, 8); qq += __shfl_xor(qq, 8);
            if (fl == 0){
                int lr = i*16 + quad*4 + r;
                psum[wave][lr] = ss; psq[wave][lr] = qq;
            }
        }
    __syncthreads();
    #pragma unroll
    for (int i = 0; i < 4; ++i)
        #pragma unroll
        for (int r = 0; r < 4; ++r){
            int lr = i*16 + quad*4 + r;
            float mu  = (psum[0][lr] + psum[1][lr] + psum[2][lr] + psum[3][lr]) * (1.0f/256.0f);
            float var = (psq[0][lr] + psq[1][lr] + psq[2][lr] + psq[3][lr]) * (1.0f/256.0f) - mu*mu;
            float rstd = rsqrtf(var + 1e-5f);
            #pragma unroll
            for (int j = 0; j < 4; ++j){
                int col = wave*64 + j*16 + fl;
                out[(size_t)(m0 + lr)*256 + col] =
                    f2bf((acc[i][j][r] - mu)*rstd*gcol[j] + bbcol[j]);
            }
        }
}

// ---------------- MFMA flash attention (in-register P via swapped QK^T) ----------------
// S^T = mfma(K, Q): lane holds S[k = nj*16+quad*4+r][q = mi*16+fl].
// P is packed to bf16 in-register (v_cvt_pk_bf16_f32) and redistributed to the
// PV A-fragment layout (k = quad*8+j) with a fixed cross-quad shfl exchange —
// no P LDS round-trip, no Ps buffer.
template<int L, bool CROSS>
__global__ __launch_bounds__(256, 3) void attn_mfma(const unsigned short* __restrict__ qkv,
    unsigned short* __restrict__ attn_out, const float* __restrict__ validf)
{
    constexpr int QW  = (L == 256) ? 64 : 16;
    constexpr int MI  = QW / 16;
    constexpr int VTS = L + 8;
    constexpr int LOG = (L == 256) ? 8 : 6;
    __shared__ unsigned short Ks[L*32];
    __shared__ unsigned short Vt[32*VTS];

    const int s = blockIdx.x, h = blockIdx.y;
    int base, stride;
    if (CROSS){ base = (s >> 8)*16384 + (s & 255); stride = 256; }
    else      { base = s << 8; stride = 1; }
    const int tid = threadIdx.x, lane = tid & 63, wave = tid >> 6;
    const int fl = lane & 15, quad = lane >> 4;
    const float scale = 0.17677669529663687f;

    // K staging, XOR-swizzled at 16B granule (source pre-swizzle, rule 21)
    for (int cid = tid; cid < L*4; cid += 256){
        int j = cid >> 2, part = (cid & 3) ^ ((cid >> 3) & 3);
        async_copy16(qkv + (size_t)(base + j*stride)*768 + 256 + h*32 + part*8, &Ks[cid*8]);
    }
    for (int e = tid; e < L*4; e += 256){
        int j = e & (L-1), dp = e >> LOG;
        uint4 vv = *(const uint4*)(qkv + (size_t)(base + j*stride)*768 + 512 + h*32 + dp*8);
        unsigned short tmp[8]; *(uint4*)tmp = vv;
        #pragma unroll
        for (int d = 0; d < 8; ++d) Vt[(dp*8 + d)*VTS + j] = tmp[d];
    }
    __syncthreads();

    bf16x8 qf[MI];
    #pragma unroll
    for (int mi = 0; mi < MI; ++mi){
        int q = wave*QW + mi*16 + fl;
        qf[mi] = *(const bf16x8*)(qkv + (size_t)(base + q*stride)*768 + h*32 + quad*8);
    }
    float vm[4][4];
    if (CROSS){
        #pragma unroll
        for (int nj = 0; nj < 4; ++nj){
            float4 v4 = *(const float4*)&validf[(s >> 8)*64 + nj*16 + quad*4];
            vm[nj][0] = v4.x; vm[nj][1] = v4.y; vm[nj][2] = v4.z; vm[nj][3] = v4.w;
        }
    }

    f32x4 oacc[MI][2] = {};
    float lpart[MI] = {};
    const int sw = (quad ^ ((fl >> 1) & 3)) << 3;
    const int la = fl | ((quad & 1) << 5);   // src lane, quads {0,2}
    const int lb = la + 16;                  // src lane, quads {1,3}

    for (int j0 = 0; j0 < L; j0 += 64){
        bf16x8 kf[4];
        #pragma unroll
        for (int nj = 0; nj < 4; ++nj)
            kf[nj] = *(const bf16x8*)&Ks[(j0 + nj*16 + fl)*32 + sw];
        unsigned int pk[MI][4][2];
        #pragma unroll
        for (int mi = 0; mi < MI; ++mi){
            f32x4 sacc[4] = {};
            #pragma unroll
            for (int nj = 0; nj < 4; ++nj)
                sacc[nj] = __builtin_amdgcn_mfma_f32_16x16x32_bf16(kf[nj], qf[mi], sacc[nj], 0, 0, 0);
            #pragma unroll
            for (int nj = 0; nj < 4; ++nj){
                float p[4];
                #pragma unroll
                for (int r = 0; r < 4; ++r){
                    float pv = __expf(sacc[nj][r] * scale);
                    if (CROSS) pv *= vm[nj][r];
                    p[r] = pv;
                    lpart[mi] += pv;
                }
                pk[mi][nj][0] = cvtpk_bf16(p[0], p[1]);
                pk[mi][nj][1] = cvtpk_bf16(p[2], p[3]);
            }
        }
        #pragma unroll
        for (int kk = 0; kk < 2; ++kk){
            bf16x8 vf[2];
            #pragma unroll
            for (int nd = 0; nd < 2; ++nd)
                vf[nd] = *(const bf16x8*)&Vt[(nd*16 + fl)*VTS + j0 + kk*32 + quad*8];
            #pragma unroll
            for (int mi = 0; mi < MI; ++mi){
                unsigned int a0 = __shfl(pk[mi][2*kk  ][0], la, 64);
                unsigned int a1 = __shfl(pk[mi][2*kk  ][1], la, 64);
                unsigned int a2 = __shfl(pk[mi][2*kk  ][0], lb, 64);
                unsigned int a3 = __shfl(pk[mi][2*kk  ][1], lb, 64);
                unsigned int b0 = __shfl(pk[mi][2*kk+1][0], la, 64);
                unsigned int b1 = __shfl(pk[mi][2*kk+1][1], la, 64);
                unsigned int b2 = __shfl(pk[mi][2*kk+1][0], lb, 64);
                unsigned int b3 = __shfl(pk[mi][2*kk+1][1], lb, 64);
                const bool lo = quad < 2;
                union { unsigned int u[4]; bf16x8 v; } pu;
                pu.u[0] = lo ? a0 : b0;
                pu.u[1] = lo ? a1 : b1;
                pu.u[2] = lo ? a2 : b2;
                pu.u[3] = lo ? a3 : b3;
                #pragma unroll
                for (int nd = 0; nd < 2; ++nd)
                    oacc[mi][nd] = __builtin_amdgcn_mfma_f32_16x16x32_bf16(pu.v, vf[nd], oacc[mi][nd], 0, 0, 0);
            }
        }
    }

    #pragma unroll
    for (int mi = 0; mi < MI; ++mi){
        float l = lpart[mi];
        l += __shfl_xor(l, 16);
        l += __shfl_xor(l, 32);
        l = 1.0f / l;
        float li[4];
        #pragma unroll
        for (int r = 0; r < 4; ++r)
            li[r] = __shfl(l, quad*4 + r, 64);
        #pragma unroll
        for (int nd = 0; nd < 2; ++nd)
            #pragma unroll
            for (int r = 0; r < 4; ++r){
                int q = wave*QW + mi*16 + quad*4 + r;
                attn_out[(size_t)(base + q*stride)*CEMB + h*32 + nd*16 + fl] =
                    f2bf(oacc[mi][nd][r] * li[r]);
            }
    }
}

// ---------------- final scatter: out = backbone + valid * x (vectorized swizzled) ----------------
// grid: 256 bw * 4 cq * 2 th = 2048 blocks; 64 c x 128 t tile per block
__global__ __launch_bounds__(256) void scatter_kernel(const float* __restrict__ bb,
    const unsigned short* __restrict__ x, const float* __restrict__ validf,
    float* __restrict__ out)
{
    __shared__ float tile[8192];
    const int bw = blockIdx.x >> 3;
    const int b = bw >> 6, w = bw & 63;
    const int cq = (blockIdx.x >> 1) & 3, th = blockIdx.x & 1;
    const int c0 = cq << 6, t0 = th << 7, y0 = th << 3;
    const int wh = w >> 3, wwi = w & 7;
    const int tid = threadIdx.x;
    const float vf = validf[bw];
    // phase 1: x (t-major bf16) -> swizzled LDS (c-major fp32)
    #pragma unroll
    for (int i = 0; i < 4; ++i){
        int n = i*256 + tid, j = n & 7, tl = n >> 3;
        int g = tl >> 2, e = tl & 3;
        uint4 xv = *(const uint4*)&x[((size_t)bw*256 + t0 + tl)*CEMB + c0 + j*8];
        float f[8]; unpack8(xv, f);
        #pragma unroll
        for (int m = 0; m < 8; ++m)
            tile[sgran(j*8 + m, g)*4 + e] = f[m];
    }
    __syncthreads();
    // phase 2: out = bb + vf * tile (c-major float4)
    const size_t gbase = ((size_t)(b*CEMB + c0))*(HH*WW) + (size_t)(wh*16 + y0)*WW + wwi*16;
    #pragma unroll
    for (int i = 0; i < 8; ++i){
        int n = i*256 + tid, slot = n & 31, c = n >> 5;
        int yl = slot >> 2, xg = slot & 3;
        size_t gi = gbase + (size_t)c*(HH*WW) + yl*WW + xg*4;
        float4 bv = *(const float4*)(bb + gi);
        float4 xv = *(const float4*)&tile[sgran(c, slot)*4];
        float4 ov;
        ov.x = bv.x + vf*xv.x; ov.y = bv.y + vf*xv.y;
        ov.z = bv.z + vf*xv.z; ov.w = bv.w + vf*xv.w;
        *(float4*)(out + gi) = ov;
    }
}

extern "C" void kernel_launch(void* const* d_in, const int* in_sizes, int n_in,
                              void* d_out, int out_size, void* d_ws, size_t ws_size,
                              hipStream_t stream)
{
    (void)in_sizes; (void)n_in; (void)out_size; (void)ws_size;
    const float* backbone = (const float*)d_in[0];
    const float* defe     = (const float*)d_in[1];
    const float* gpe      = (const float*)d_in[3];
    const float* rw1 = (const float*)d_in[4];
    const float* rb1 = (const float*)d_in[5];
    const float* rw2 = (const float*)d_in[6];
    const float* rb2 = (const float*)d_in[7];
    const float* ipw = (const float*)d_in[8];
    const float* ipb = (const float*)d_in[9];
    const float* opw = (const float*)d_in[10];
    const float* opb = (const float*)d_in[11];
    const float* l1w = (const float*)d_in[12];
    const float* l1b = (const float*)d_in[13];
    const float* l2w = (const float*)d_in[14];
    const float* l2b = (const float*)d_in[15];
    const float* g1  = (const float*)d_in[16];
    const float* b1  = (const float*)d_in[17];
    const float* g2  = (const float*)d_in[18];
    const float* b2  = (const float*)d_in[19];

    char* ws = (char*)d_ws;
    unsigned short* pos    = (unsigned short*)(ws);               //   8,388,608
    unsigned short* x      = (unsigned short*)(ws +   8388608);   //  33,554,432
    unsigned short* qkv    = (unsigned short*)(ws +  41943040);   // 100,663,296 (src = qkv)
    unsigned short* shared_= (unsigned short*)(ws + 142606336);   //  33,554,432 (xp -> attn)
    float*          validf = (float*)(ws + 176160768);            //       1,024
    unsigned short* ipw16  = (unsigned short*)(ws + 176161792);
    unsigned short* opw16  = (unsigned short*)(ws + 176555008);
    unsigned short* l1w16  = (unsigned short*)(ws + 176686080);
    unsigned short* l2w16  = (unsigned short*)(ws + 177210368);
    float*          rel    = (float*)(ws + 177734656);
    unsigned short* src = qkv;
    float* outf = (float*)d_out;

    wcvt_kernel<<<192, 256, 0, stream>>>(ipw, ipw16, 49152);
    wcvt_kernel<<< 64, 256, 0, stream>>>(opw, opw16, 16384);
    wcvt_kernel<<<256, 256, 0, stream>>>(l1w, l1w16, 65536);
    wcvt_kernel<<<256, 256, 0, stream>>>(l2w, l2w16, 65536);
    rel_kernel<<<256, 256, 0, stream>>>(rw1, rb1, rw2, rb2, rel);
    posT_kernel<<<512, 256, 0, stream>>>(gpe, rel, pos);
    valid_kernel<<<BB*NW, 256, 0, stream>>>(defe, validf, outf + (size_t)BB*CEMB*HH*WW);
    partition_kernel<<<2048, 256, 0, stream>>>(backbone, x);

    for (int layer = 0; layer < 2; ++layer){
        addpos_kernel<<<8192, 256, 0, stream>>>(x, pos, shared_);
        gemm_mfma<<<dim3(512, 6), 256, 0, stream>>>(shared_, x, 512, CEMB, ipw16, CEMB, ipb, qkv, 768, 0);
        if (layer == 0)
            attn_mfma<256, false><<<dim3(BB*NW, NHEAD), 256, 0, stream>>>(qkv, shared_, validf);
        else
            attn_mfma<64, true><<<dim3(BB*TT, NHEAD), 256, 0, stream>>>(qkv, shared_, validf);
        gemm_ln<<<dim3(1024, 1), 256, 0, stream>>>(shared_, CEMB, opw16, opb, x, g1, b1, src);
        ffn_fused<<<1024, 256, 0, stream>>>(src, l1w16, l1b, l2w16, l2b, g2, b2, x);
    }
    scatter_kernel<<<2048, 256, 0, stream>>>(backbone, x, validf, outf);
}

// Round 5
// 800.770 us; speedup vs baseline: 1.1260x; 1.1260x over previous
//
#include <hip/hip_runtime.h>
#include <hip/hip_bf16.h>

// ---------------- problem constants ----------------
#define CEMB 256
#define NHEAD 8
#define DHEAD 32
#define DFF 1024
#define BB 4
#define HH 128
#define WW 128
#define WSZ 16
#define NWH 8
#define NW 64
#define TT 256            // tokens per window
#define NTOK (BB*NW*TT)   // 65536

typedef __attribute__((ext_vector_type(8))) short bf16x8;
typedef __attribute__((ext_vector_type(4))) float f32x4;

// bf16 helpers (storage type = ushort)
__device__ __forceinline__ float bf2f(unsigned short u){
    union { float f; unsigned int i; } v; v.i = ((unsigned int)u) << 16; return v.f;
}
__device__ __forceinline__ unsigned short f2bf(float f){
    union { float f; unsigned int i; } v; v.f = f;
    unsigned int r = v.i + 0x7fffu + ((v.i >> 16) & 1u);
    return (unsigned short)(r >> 16);
}
__device__ __forceinline__ unsigned int cvtpk_bf16(float lo, float hi){
    unsigned int r;
    asm("v_cvt_pk_bf16_f32 %0, %1, %2" : "=v"(r) : "v"(lo), "v"(hi));
    return r;
}
__device__ __forceinline__ void unpack8(uint4 v, float* f){
    f[0]=bf2f((unsigned short)(v.x & 0xffff)); f[1]=bf2f((unsigned short)(v.x>>16));
    f[2]=bf2f((unsigned short)(v.y & 0xffff)); f[3]=bf2f((unsigned short)(v.y>>16));
    f[4]=bf2f((unsigned short)(v.z & 0xffff)); f[5]=bf2f((unsigned short)(v.z>>16));
    f[6]=bf2f((unsigned short)(v.w & 0xffff)); f[7]=bf2f((unsigned short)(v.w>>16));
}
__device__ __forceinline__ void async_copy16(const void* g, void* l){
    __builtin_amdgcn_global_load_lds(
        (const __attribute__((address_space(1))) unsigned int*)g,
        (__attribute__((address_space(3))) unsigned int*)l, 16, 0, 0);
}
// xor-swizzled LDS granule index for 64c x 128t fp32 transpose tiles
// (granule = 4 floats along t; phys granule = c*32 + (g ^ (c&31)))
__device__ __forceinline__ int sgran(int c, int g){ return c*32 + (g ^ (c & 31)); }

// ---------------- rel MLP: rel[t][c] fp32 (once) ----------------
__global__ __launch_bounds__(256) void rel_kernel(const float* __restrict__ rw1,
    const float* __restrict__ rb1, const float* __restrict__ rw2,
    const float* __restrict__ rb2, float* __restrict__ rel)
{
    __shared__ float hsh[64];
    int t = blockIdx.x, c = threadIdx.x;
    int ty = t >> 4, tx = t & 15;
    if (c < 64){
        float y = ty*(1.0f/15.0f), xx = tx*(1.0f/15.0f);
        hsh[c] = fmaxf(y*rw1[2*c] + xx*rw1[2*c+1] + rb1[c], 0.0f);
    }
    __syncthreads();
    float acc = rb2[c];
    #pragma unroll 16
    for (int k = 0; k < 64; ++k) acc += hsh[k]*rw2[c*64 + k];
    rel[t*256 + c] = acc;
}

// ---------------- pos[w][t][c] = gp^T + rel  (vectorized swizzled transpose) ----------------
// grid: 64 w * 4 cq * 2 th = 512 blocks; 64 c x 128 t tile per block
__global__ __launch_bounds__(256) void posT_kernel(const float* __restrict__ gp,
    const float* __restrict__ rel, unsigned short* __restrict__ pos)
{
    __shared__ float tile[8192];
    const int w  = blockIdx.x >> 3;
    const int cq = (blockIdx.x >> 1) & 3, th = blockIdx.x & 1;
    const int c0 = cq << 6, t0 = th << 7, y0 = th << 3;
    const int wh = w >> 3, wwi = w & 7;
    const int tid = threadIdx.x;
    const float* gpb = gp + (size_t)c0*(HH*WW) + (size_t)(wh*16 + y0)*WW + wwi*16;
    #pragma unroll
    for (int i = 0; i < 8; ++i){
        int n = i*256 + tid, slot = n & 31, c = n >> 5;
        int yl = slot >> 2, xg = slot & 3;
        float4 v = *(const float4*)(gpb + (size_t)c*(HH*WW) + yl*WW + xg*4);
        *(float4*)&tile[sgran(c, slot)*4] = v;
    }
    __syncthreads();
    #pragma unroll
    for (int i = 0; i < 4; ++i){
        int n = i*256 + tid, j = n & 7, tl = n >> 3;
        int g = tl >> 2, e = tl & 3;
        const float* rl = rel + (t0 + tl)*256 + c0 + j*8;
        unsigned short o[8];
        #pragma unroll
        for (int m = 0; m < 8; ++m)
            o[m] = f2bf(tile[sgran(j*8 + m, g)*4 + e] + rl[m]);
        *(uint4*)&pos[((size_t)w*256 + t0 + tl)*CEMB + c0 + j*8] = *(uint4*)o;
    }
}

// ---------------- K2: window validity (max-pool > 0) ----------------
__global__ __launch_bounds__(256) void valid_kernel(const float* __restrict__ defe,
    float* __restrict__ validf, float* __restrict__ tail)
{
    __shared__ float red[4];
    int bw = blockIdx.x; int b = bw >> 6, w = bw & 63;
    int t = threadIdx.x; int ty = t >> 4, tx = t & 15;
    int wh = w >> 3, wwi = w & 7;
    float v = defe[(size_t)b*(HH*WW) + (wh*16+ty)*WW + wwi*16 + tx];
    int lane = t & 63, wave = t >> 6;
    for (int off = 1; off < 64; off <<= 1) v = fmaxf(v, __shfl_xor(v, off));
    if (lane == 0) red[wave] = v;
    __syncthreads();
    if (t == 0){
        float m = fmaxf(fmaxf(red[0], red[1]), fmaxf(red[2], red[3]));
        float r = (m > 0.0f) ? 1.0f : 0.0f;
        validf[bw] = r;
        tail[bw] = r;
    }
}

// ---------------- K3: window partition  backbone[B,C,H,W] -> x[b,w,t,c] bf16 ----------------
// grid: 256 bw * 4 cq * 2 th = 2048 blocks; 64 c x 128 t tile per block
__global__ __launch_bounds__(256) void partition_kernel(const float* __restrict__ bb,
    unsigned short* __restrict__ x)
{
    __shared__ float tile[8192];
    const int bw = blockIdx.x >> 3;
    const int b = bw >> 6, w = bw & 63;
    const int cq = (blockIdx.x >> 1) & 3, th = blockIdx.x & 1;
    const int c0 = cq << 6, t0 = th << 7, y0 = th << 3;
    const int wh = w >> 3, wwi = w & 7;
    const int tid = threadIdx.x;
    const float* bbb = bb + ((size_t)(b*CEMB + c0))*(HH*WW) + (size_t)(wh*16 + y0)*WW + wwi*16;
    #pragma unroll
    for (int i = 0; i < 8; ++i){
        int n = i*256 + tid, slot = n & 31, c = n >> 5;
        int yl = slot >> 2, xg = slot & 3;
        float4 v = *(const float4*)(bbb + (size_t)c*(HH*WW) + yl*WW + xg*4);
        *(float4*)&tile[sgran(c, slot)*4] = v;
    }
    __syncthreads();
    #pragma unroll
    for (int i = 0; i < 4; ++i){
        int n = i*256 + tid, j = n & 7, tl = n >> 3;
        int g = tl >> 2, e = tl & 3;
        unsigned short o[8];
        #pragma unroll
        for (int m = 0; m < 8; ++m)
            o[m] = f2bf(tile[sgran(j*8 + m, g)*4 + e]);
        *(uint4*)&x[((size_t)bw*256 + t0 + tl)*CEMB + c0 + j*8] = *(uint4*)o;
    }
}

// ---------------- weight fp32 -> bf16 ----------------
__global__ __launch_bounds__(256) void wcvt_kernel(const float* __restrict__ w,
    unsigned short* __restrict__ o, int n4)
{
    int i = blockIdx.x*256 + threadIdx.x;
    if (i < n4){
        float4 v = ((const float4*)w)[i];
        ushort4 u;
        u.x = f2bf(v.x); u.y = f2bf(v.y); u.z = f2bf(v.z); u.w = f2bf(v.w);
        ((ushort4*)o)[i] = u;
    }
}

// ---------------- xp = x + pos (bf16 elementwise, 8 el/thread) ----------------
__global__ __launch_bounds__(256) void addpos_kernel(const unsigned short* __restrict__ x,
    const unsigned short* __restrict__ pos, unsigned short* __restrict__ xp)
{
    size_t i = ((size_t)blockIdx.x*256 + threadIdx.x) * 8;
    size_t tok = i >> 8; int c = (int)(i & 255);
    size_t pi = ((tok & 16383) << 8) + c;
    uint4 xv = *(const uint4*)&x[i];
    uint4 pv = *(const uint4*)&pos[pi];
    float xf[8], pf[8]; unpack8(xv, xf); unpack8(pv, pf);
    unsigned short o[8];
    #pragma unroll
    for (int j = 0; j < 8; ++j) o[j] = f2bf(xf[j] + pf[j]);
    *(uint4*)&xp[i] = *(uint4*)o;
}

// ---------------- MFMA GEMM: out[M,N](bf16) = A[M,K](bf16) @ W[N,K]^T + bias ----------------
// K-tile LDS layout is XOR-swizzled at 16B granule: phys granule (r, g) holds
// logical granule (r, g ^ ((r>>1)&3)).  global_load_lds writes linearly, so the
// swizzle is applied by pre-swizzling the *source* offset; reads XOR the granule.
__global__ __launch_bounds__(256) void gemm_mfma(
    const unsigned short* __restrict__ A,
    const unsigned short* __restrict__ A2, int nsplit, int ldA,
    const unsigned short* __restrict__ W, int K,
    const float* __restrict__ bias,
    unsigned short* __restrict__ out, int ldO, int relu)
{
    __shared__ unsigned short As[128*32];
    __shared__ unsigned short Bs[128*32];
    const int m0 = blockIdx.x << 7, n0 = blockIdx.y << 7;
    const int tid = threadIdx.x;
    const int lane = tid & 63, wave = tid >> 6;
    const int wm = wave & 1, wn = wave >> 1;
    const int fl = lane & 15, quad = lane >> 4;

    const unsigned short* Ap = ((n0 < nsplit) ? A : A2) + (size_t)m0*ldA;
    const unsigned short* Wp = W + (size_t)n0*K;

    const int c0 = tid, c1 = tid + 256;
    const int r0 = c0 >> 2, o0 = ((c0 & 3) ^ ((c0 >> 3) & 3)) << 3;
    const int r1 = c1 >> 2, o1 = ((c1 & 3) ^ ((c1 >> 3) & 3)) << 3;
    // read-side swizzle: row bits 1..2 == fl bits 1..2 (i*16, wm*64 don't touch them)
    const int sw = (quad ^ ((fl >> 1) & 3)) << 3;

    f32x4 acc[4][4] = {};

    for (int k0 = 0; k0 < K; k0 += 32){
        async_copy16(Ap + (size_t)r0*ldA + k0 + o0, &As[c0 << 3]);
        async_copy16(Ap + (size_t)r1*ldA + k0 + o1, &As[c1 << 3]);
        async_copy16(Wp + (size_t)r0*K   + k0 + o0, &Bs[c0 << 3]);
        async_copy16(Wp + (size_t)r1*K   + k0 + o1, &Bs[c1 << 3]);
        __syncthreads();
        bf16x8 av[4], bv[4];
        #pragma unroll
        for (int i = 0; i < 4; ++i){
            av[i] = *(const bf16x8*)&As[(wm*64 + i*16 + fl)*32 + sw];
            bv[i] = *(const bf16x8*)&Bs[(wn*64 + i*16 + fl)*32 + sw];
        }
        #pragma unroll
        for (int i = 0; i < 4; ++i)
            #pragma unroll
            for (int j = 0; j < 4; ++j)
                acc[i][j] = __builtin_amdgcn_mfma_f32_16x16x32_bf16(av[i], bv[j], acc[i][j], 0, 0, 0);
        __syncthreads();
    }

    float bj[4];
    #pragma unroll
    for (int j = 0; j < 4; ++j) bj[j] = bias[n0 + wn*64 + j*16 + fl];
    #pragma unroll
    for (int i = 0; i < 4; ++i){
        int mrow = m0 + wm*64 + i*16 + quad*4;
        #pragma unroll
        for (int j = 0; j < 4; ++j){
            int col = n0 + wn*64 + j*16 + fl;
            #pragma unroll
            for (int r = 0; r < 4; ++r){
                float v = acc[i][j][r] + bj[j];
                if (relu) v = fmaxf(v, 0.0f);
                out[(size_t)(mrow + r)*ldO + col] = f2bf(v);
            }
        }
    }
}

// ---------------- MFMA GEMM + residual + LayerNorm (N == 256 exactly) ----------------
// 64-row tile, 4 waves each owning a 64x64 quadrant of columns: acc = 64 f32/lane
__global__ __launch_bounds__(256, 3) void gemm_ln(
    const unsigned short* __restrict__ A, int K,
    const unsigned short* __restrict__ W,
    const float* __restrict__ bias,
    const unsigned short* __restrict__ resid,
    const float* __restrict__ g, const float* __restrict__ b,
    unsigned short* __restrict__ out)
{
    __shared__ unsigned short As[64*32];
    __shared__ unsigned short Bs[256*32];
    __shared__ float psum[4][64];
    __shared__ float psq[4][64];
    const int m0 = blockIdx.x << 6;
    const int tid = threadIdx.x, lane = tid & 63, wave = tid >> 6;
    const int wn = wave;
    const int fl = lane & 15, quad = lane >> 4;

    const unsigned short* Ap = A + (size_t)m0*K;

    const int ra = tid >> 2, oa = ((tid & 3) ^ ((tid >> 3) & 3)) << 3;
    const int sw = (quad ^ ((fl >> 1) & 3)) << 3;

    f32x4 acc[4][4] = {};

    for (int k0 = 0; k0 < K; k0 += 32){
        async_copy16(Ap + (size_t)ra*K + k0 + oa, &As[tid << 3]);
        #pragma unroll
        for (int t = 0; t < 4; ++t){
            int c = tid + t*256;
            int r = c >> 2, o = ((c & 3) ^ ((c >> 3) & 3)) << 3;
            async_copy16(W + (size_t)r*K + k0 + o, &Bs[c << 3]);
        }
        __syncthreads();
        bf16x8 av[4], bv[4];
        #pragma unroll
        for (int i = 0; i < 4; ++i)
            av[i] = *(const bf16x8*)&As[(i*16 + fl)*32 + sw];
        #pragma unroll
        for (int j = 0; j < 4; ++j)
            bv[j] = *(const bf16x8*)&Bs[(wn*64 + j*16 + fl)*32 + sw];
        #pragma unroll
        for (int i = 0; i < 4; ++i)
            #pragma unroll
            for (int j = 0; j < 4; ++j)
                acc[i][j] = __builtin_amdgcn_mfma_f32_16x16x32_bf16(av[i], bv[j], acc[i][j], 0, 0, 0);
        __syncthreads();
    }

    float bcol[4], gcol[4], bbcol[4];
    #pragma unroll
    for (int j = 0; j < 4; ++j){
        int col = wn*64 + j*16 + fl;
        bcol[j] = bias[col]; gcol[j] = g[col]; bbcol[j] = b[col];
    }
    float s[4][4] = {{0}}, sq[4][4] = {{0}};
    #pragma unroll
    for (int i = 0; i < 4; ++i)
        #pragma unroll
        for (int r = 0; r < 4; ++r){
            int row = m0 + i*16 + quad*4 + r;
            #pragma unroll
            for (int j = 0; j < 4; ++j){
                float h = acc[i][j][r] + bcol[j]
                        + bf2f(resid[(size_t)row*256 + wn*64 + j*16 + fl]);
                acc[i][j][r] = h;
                s[i][r] += h; sq[i][r] += h*h;
            }
        }
    #pragma unroll
    for (int i = 0; i < 4; ++i)
        #pragma unroll
        for (int r = 0; r < 4; ++r){
            float ss = s[i][r], qq = sq[i][r];
            ss += __shfl_xor(ss, 1); qq += __shfl_xor(qq, 1);
            ss += __shfl_xor(ss, 2); qq += __shfl_xor(qq, 2);
            ss += __shfl_xor(ss, 4); qq += __shfl_xor(qq, 4);
            ss += __shfl_xor(ss, 8); qq += __shfl_xor(qq, 8);
            if (fl == 0){
                int lr = i*16 + quad*4 + r;
                psum[wn][lr] = ss; psq[wn][lr] = qq;
            }
        }
    __syncthreads();
    #pragma unroll
    for (int i = 0; i < 4; ++i)
        #pragma unroll
        for (int r = 0; r < 4; ++r){
            int lr = i*16 + quad*4 + r;
            float mu  = (psum[0][lr] + psum[1][lr] + psum[2][lr] + psum[3][lr]) * (1.0f/256.0f);
            float var = (psq[0][lr] + psq[1][lr] + psq[2][lr] + psq[3][lr]) * (1.0f/256.0f) - mu*mu;
            float rstd = rsqrtf(var + 1e-5f);
            #pragma unroll
            for (int j = 0; j < 4; ++j){
                int col = wn*64 + j*16 + fl;
                out[(size_t)(m0 + lr)*256 + col] =
                    f2bf((acc[i][j][r] - mu)*rstd*gcol[j] + bbcol[j]);
            }
        }
}

// ---------------- fused FFN: out = LN2( src + relu(src@W1^T+b1)@W2^T + b2 ) ----------------
// 64-row block, 4 waves. Hidden in 16 chunks of 64. Weight chunks (32KB each)
// are STAGED INTO LDS with coalesced global_load_lds (R4's direct global
// fragment reads were uncoalesced 16B @ 512B stride — the 215us stall).
// Staging is software-pipelined: W2(c) staged under GEMM1(c), W1(c+1) staged
// under GEMM2(c); the existing two barriers per chunk drain vmcnt for free.
// GEMM1 = swapped-operand MFMA (h^T), relu+bias, cvt_pk into 8KB swizzled
// hlds; GEMM2 accumulates standard C layout; epilogue = residual + LN.
__global__ __launch_bounds__(256, 2) void ffn_fused(
    const unsigned short* __restrict__ src,
    const unsigned short* __restrict__ w1,   // [1024][256] bf16
    const float* __restrict__ b1,
    const unsigned short* __restrict__ w2,   // [256][1024] bf16
    const float* __restrict__ b2,
    const float* __restrict__ g, const float* __restrict__ b,
    unsigned short* __restrict__ out)
{
    __shared__ unsigned short w1buf[64*256]; // 32KB  W1 chunk, granule-swizzled
    __shared__ unsigned short w2buf[256*64]; // 32KB  W2 chunk, granule-swizzled
    __shared__ unsigned short hlds[64*64];   // 8KB   h tile
    __shared__ float psum[4][64];
    __shared__ float psq[4][64];
    const int m0 = blockIdx.x << 6;
    const int tid = threadIdx.x, lane = tid & 63, wave = tid >> 6;
    const int fl = lane & 15, quad = lane >> 4;
    const int fsl = fl & 7;

    // persistent src fragments: qf[mi][kf] = src[m0+mi*16+fl][kf*32+quad*8 ..+8]
    bf16x8 qf[4][8];
    #pragma unroll
    for (int mi = 0; mi < 4; ++mi)
        #pragma unroll
        for (int kf = 0; kf < 8; ++kf)
            qf[mi][kf] = *(const bf16x8*)&src[(size_t)(m0 + mi*16 + fl)*256 + kf*32 + quad*8];

    f32x4 acc[4][4] = {};
    const int gwr = wave*2 + (quad >> 1);    // write-side h granule
    const int who = (quad & 1) << 2;         // within-granule ushort offset

    // prologue: stage W1 chunk 0 (rows 0..63), source-preswizzled granules
    #pragma unroll
    for (int i = 0; i < 8; ++i){
        int G = i*256 + tid, hid = G >> 5, gp = G & 31;
        async_copy16(w1 + (size_t)hid*256 + ((gp ^ (hid & 7)) << 3), &w1buf[G << 3]);
    }
    __syncthreads();

    for (int c = 0; c < 16; ++c){
        const int j0 = c << 6;
        // stage W2 chunk c (overlaps GEMM1; drained by barrier below)
        #pragma unroll
        for (int i = 0; i < 8; ++i){
            int G = i*256 + tid, oc = G >> 3, gp = G & 7;
            async_copy16(w2 + (size_t)oc*1024 + j0 + ((gp ^ (oc & 7)) << 3), &w2buf[G << 3]);
        }
        // ---- GEMM1: h^T[16 hid (this wave)][64 rows] = W1c . src^T ----
        bf16x8 w1f[8];
        #pragma unroll
        for (int kf = 0; kf < 8; ++kf)
            w1f[kf] = *(const bf16x8*)&w1buf[(((wave*16 + fl) << 5) + ((kf*4 + quad) ^ fsl)) << 3];
        float4 b1v = *(const float4*)&b1[j0 + wave*16 + quad*4];
        #pragma unroll
        for (int mi = 0; mi < 4; ++mi){
            f32x4 sacc = {};
            #pragma unroll
            for (int kf = 0; kf < 8; ++kf)
                sacc = __builtin_amdgcn_mfma_f32_16x16x32_bf16(w1f[kf], qf[mi][kf], sacc, 0, 0, 0);
            // lane holds h[hid = wave*16+quad*4+r][row = mi*16+fl]
            float h0 = fmaxf(sacc[0] + b1v.x, 0.0f);
            float h1 = fmaxf(sacc[1] + b1v.y, 0.0f);
            float h2 = fmaxf(sacc[2] + b1v.z, 0.0f);
            float h3 = fmaxf(sacc[3] + b1v.w, 0.0f);
            int r_ = mi*16 + fl;
            int gb = r_*64 + ((gwr ^ fsl) << 3) + who;
            *(unsigned int*)&hlds[gb    ] = cvtpk_bf16(h0, h1);
            *(unsigned int*)&hlds[gb + 2] = cvtpk_bf16(h2, h3);
        }
        __syncthreads();   // hlds ready + W2(c) staged
        // stage W1 chunk c+1 (overlaps GEMM2; drained by barrier below)
        if (c < 15){
            #pragma unroll
            for (int i = 0; i < 8; ++i){
                int G = i*256 + tid, hid = G >> 5, gp = G & 31;
                async_copy16(w1 + (size_t)(j0 + 64 + hid)*256 + ((gp ^ (hid & 7)) << 3), &w1buf[G << 3]);
            }
        }
        // ---- GEMM2: acc += h . W2c^T ----
        #pragma unroll
        for (int kk = 0; kk < 2; ++kk){
            bf16x8 hf[4], w2f[4];
            #pragma unroll
            for (int mi = 0; mi < 4; ++mi)
                hf[mi] = *(const bf16x8*)&hlds[(mi*16 + fl)*64 + (((kk*4 + quad) ^ fsl) << 3)];
            #pragma unroll
            for (int nd = 0; nd < 4; ++nd)
                w2f[nd] = *(const bf16x8*)&w2buf[(((wave*64 + nd*16 + fl) << 3) + ((kk*4 + quad) ^ fsl)) << 3];
            #pragma unroll
            for (int mi = 0; mi < 4; ++mi)
                #pragma unroll
                for (int nd = 0; nd < 4; ++nd)
                    acc[mi][nd] = __builtin_amdgcn_mfma_f32_16x16x32_bf16(hf[mi], w2f[nd], acc[mi][nd], 0, 0, 0);
        }
        __syncthreads();   // W1(c+1) staged; hlds/w2buf reusable
    }

    // ---- epilogue: + b2 + resid(src), LayerNorm(g,b) -> out ----
    float bcol[4], gcol[4], bbcol[4];
    #pragma unroll
    for (int j = 0; j < 4; ++j){
        int col = wave*64 + j*16 + fl;
        bcol[j] = b2[col]; gcol[j] = g[col]; bbcol[j] = b[col];
    }
    float s[4][4] = {{0}}, sq[4][4] = {{0}};
    #pragma unroll
    for (int i = 0; i < 4; ++i)
        #pragma unroll
        for (int r = 0; r < 4; ++r){
            int row = m0 + i*16 + quad*4 + r;
            #pragma unroll
            for (int j = 0; j < 4; ++j){
                float h = acc[i][j][r] + bcol[j]
                        + bf2f(src[(size_t)row*256 + wave*64 + j*16 + fl]);
                acc[i][j][r] = h;
                s[i][r] += h; sq[i][r] += h*h;
            }
        }
    #pragma unroll
    for (int i = 0; i < 4; ++i)
        #pragma unroll
        for (int r = 0; r < 4; ++r){
            float ss = s[i][r], qq = sq[i][r];
            ss += __shfl_xor(ss, 1); qq += __shfl_xor(qq, 1);
            ss += __shfl_xor(ss, 2); qq += __shfl_xor(qq, 2);
            ss += __shfl_xor(ss, 4); qq += __shfl_xor(qq, 4);
            ss += __shfl_xor(ss, 8); qq += __shfl_xor(qq, 8);
            if (fl == 0){
                int lr = i*16 + quad*4 + r;
                psum[wave][lr] = ss; psq[wave][lr] = qq;
            }
        }
    __syncthreads();
    #pragma unroll
    for (int i = 0; i < 4; ++i)
        #pragma unroll
        for (int r = 0; r < 4; ++r){
            int lr = i*16 + quad*4 + r;
            float mu  = (psum[0][lr] + psum[1][lr] + psum[2][lr] + psum[3][lr]) * (1.0f/256.0f);
            float var = (psq[0][lr] + psq[1][lr] + psq[2][lr] + psq[3][lr]) * (1.0f/256.0f) - mu*mu;
            float rstd = rsqrtf(var + 1e-5f);
            #pragma unroll
            for (int j = 0; j < 4; ++j){
                int col = wave*64 + j*16 + fl;
                out[(size_t)(m0 + lr)*256 + col] =
                    f2bf((acc[i][j][r] - mu)*rstd*gcol[j] + bbcol[j]);
            }
        }
}

// ---------------- MFMA flash attention (in-register P via swapped QK^T) ----------------
// S^T = mfma(K, Q): lane holds S[k = nj*16+quad*4+r][q = mi*16+fl].
// P is packed to bf16 in-register (v_cvt_pk_bf16_f32) and redistributed to the
// PV A-fragment layout (k = quad*8+j) with a fixed cross-quad shfl exchange —
// no P LDS round-trip, no Ps buffer.
template<int L, bool CROSS>
__global__ __launch_bounds__(256, 3) void attn_mfma(const unsigned short* __restrict__ qkv,
    unsigned short* __restrict__ attn_out, const float* __restrict__ validf)
{
    constexpr int QW  = (L == 256) ? 64 : 16;
    constexpr int MI  = QW / 16;
    constexpr int VTS = L + 8;
    constexpr int LOG = (L == 256) ? 8 : 6;
    __shared__ unsigned short Ks[L*32];
    __shared__ unsigned short Vt[32*VTS];

    const int s = blockIdx.x, h = blockIdx.y;
    int base, stride;
    if (CROSS){ base = (s >> 8)*16384 + (s & 255); stride = 256; }
    else      { base = s << 8; stride = 1; }
    const int tid = threadIdx.x, lane = tid & 63, wave = tid >> 6;
    const int fl = lane & 15, quad = lane >> 4;
    const float scale = 0.17677669529663687f;

    // K staging, XOR-swizzled at 16B granule (source pre-swizzle, rule 21)
    for (int cid = tid; cid < L*4; cid += 256){
        int j = cid >> 2, part = (cid & 3) ^ ((cid >> 3) & 3);
        async_copy16(qkv + (size_t)(base + j*stride)*768 + 256 + h*32 + part*8, &Ks[cid*8]);
    }
    for (int e = tid; e < L*4; e += 256){
        int j = e & (L-1), dp = e >> LOG;
        uint4 vv = *(const uint4*)(qkv + (size_t)(base + j*stride)*768 + 512 + h*32 + dp*8);
        unsigned short tmp[8]; *(uint4*)tmp = vv;
        #pragma unroll
        for (int d = 0; d < 8; ++d) Vt[(dp*8 + d)*VTS + j] = tmp[d];
    }
    __syncthreads();

    bf16x8 qf[MI];
    #pragma unroll
    for (int mi = 0; mi < MI; ++mi){
        int q = wave*QW + mi*16 + fl;
        qf[mi] = *(const bf16x8*)(qkv + (size_t)(base + q*stride)*768 + h*32 + quad*8);
    }
    float vm[4][4];
    if (CROSS){
        #pragma unroll
        for (int nj = 0; nj < 4; ++nj){
            float4 v4 = *(const float4*)&validf[(s >> 8)*64 + nj*16 + quad*4];
            vm[nj][0] = v4.x; vm[nj][1] = v4.y; vm[nj][2] = v4.z; vm[nj][3] = v4.w;
        }
    }

    f32x4 oacc[MI][2] = {};
    float lpart[MI] = {};
    const int sw = (quad ^ ((fl >> 1) & 3)) << 3;
    const int la = fl | ((quad & 1) << 5);   // src lane, quads {0,2}
    const int lb = la + 16;                  // src lane, quads {1,3}

    for (int j0 = 0; j0 < L; j0 += 64){
        bf16x8 kf[4];
        #pragma unroll
        for (int nj = 0; nj < 4; ++nj)
            kf[nj] = *(const bf16x8*)&Ks[(j0 + nj*16 + fl)*32 + sw];
        unsigned int pk[MI][4][2];
        #pragma unroll
        for (int mi = 0; mi < MI; ++mi){
            f32x4 sacc[4] = {};
            #pragma unroll
            for (int nj = 0; nj < 4; ++nj)
                sacc[nj] = __builtin_amdgcn_mfma_f32_16x16x32_bf16(kf[nj], qf[mi], sacc[nj], 0, 0, 0);
            #pragma unroll
            for (int nj = 0; nj < 4; ++nj){
                float p[4];
                #pragma unroll
                for (int r = 0; r < 4; ++r){
                    float pv = __expf(sacc[nj][r] * scale);
                    if (CROSS) pv *= vm[nj][r];
                    p[r] = pv;
                    lpart[mi] += pv;
                }
                pk[mi][nj][0] = cvtpk_bf16(p[0], p[1]);
                pk[mi][nj][1] = cvtpk_bf16(p[2], p[3]);
            }
        }
        #pragma unroll
        for (int kk = 0; kk < 2; ++kk){
            bf16x8 vf[2];
            #pragma unroll
            for (int nd = 0; nd < 2; ++nd)
                vf[nd] = *(const bf16x8*)&Vt[(nd*16 + fl)*VTS + j0 + kk*32 + quad*8];
            #pragma unroll
            for (int mi = 0; mi < MI; ++mi){
                unsigned int a0 = __shfl(pk[mi][2*kk  ][0], la, 64);
                unsigned int a1 = __shfl(pk[mi][2*kk  ][1], la, 64);
                unsigned int a2 = __shfl(pk[mi][2*kk  ][0], lb, 64);
                unsigned int a3 = __shfl(pk[mi][2*kk  ][1], lb, 64);
                unsigned int b0 = __shfl(pk[mi][2*kk+1][0], la, 64);
                unsigned int b1 = __shfl(pk[mi][2*kk+1][1], la, 64);
                unsigned int b2 = __shfl(pk[mi][2*kk+1][0], lb, 64);
                unsigned int b3 = __shfl(pk[mi][2*kk+1][1], lb, 64);
                const bool lo = quad < 2;
                union { unsigned int u[4]; bf16x8 v; } pu;
                pu.u[0] = lo ? a0 : b0;
                pu.u[1] = lo ? a1 : b1;
                pu.u[2] = lo ? a2 : b2;
                pu.u[3] = lo ? a3 : b3;
                #pragma unroll
                for (int nd = 0; nd < 2; ++nd)
                    oacc[mi][nd] = __builtin_amdgcn_mfma_f32_16x16x32_bf16(pu.v, vf[nd], oacc[mi][nd], 0, 0, 0);
            }
        }
    }

    #pragma unroll
    for (int mi = 0; mi < MI; ++mi){
        float l = lpart[mi];
        l += __shfl_xor(l, 16);
        l += __shfl_xor(l, 32);
        l = 1.0f / l;
        float li[4];
        #pragma unroll
        for (int r = 0; r < 4; ++r)
            li[r] = __shfl(l, quad*4 + r, 64);
        #pragma unroll
        for (int nd = 0; nd < 2; ++nd)
            #pragma unroll
            for (int r = 0; r < 4; ++r){
                int q = wave*QW + mi*16 + quad*4 + r;
                attn_out[(size_t)(base + q*stride)*CEMB + h*32 + nd*16 + fl] =
                    f2bf(oacc[mi][nd][r] * li[r]);
            }
    }
}

// ---------------- final scatter: out = backbone + valid * x (vectorized swizzled) ----------------
// grid: 256 bw * 4 cq * 2 th = 2048 blocks; 64 c x 128 t tile per block
__global__ __launch_bounds__(256) void scatter_kernel(const float* __restrict__ bb,
    const unsigned short* __restrict__ x, const float* __restrict__ validf,
    float* __restrict__ out)
{
    __shared__ float tile[8192];
    const int bw = blockIdx.x >> 3;
    const int b = bw >> 6, w = bw & 63;
    const int cq = (blockIdx.x >> 1) & 3, th = blockIdx.x & 1;
    const int c0 = cq << 6, t0 = th << 7, y0 = th << 3;
    const int wh = w >> 3, wwi = w & 7;
    const int tid = threadIdx.x;
    const float vf = validf[bw];
    // phase 1: x (t-major bf16) -> swizzled LDS (c-major fp32)
    #pragma unroll
    for (int i = 0; i < 4; ++i){
        int n = i*256 + tid, j = n & 7, tl = n >> 3;
        int g = tl >> 2, e = tl & 3;
        uint4 xv = *(const uint4*)&x[((size_t)bw*256 + t0 + tl)*CEMB + c0 + j*8];
        float f[8]; unpack8(xv, f);
        #pragma unroll
        for (int m = 0; m < 8; ++m)
            tile[sgran(j*8 + m, g)*4 + e] = f[m];
    }
    __syncthreads();
    // phase 2: out = bb + vf * tile (c-major float4)
    const size_t gbase = ((size_t)(b*CEMB + c0))*(HH*WW) + (size_t)(wh*16 + y0)*WW + wwi*16;
    #pragma unroll
    for (int i = 0; i < 8; ++i){
        int n = i*256 + tid, slot = n & 31, c = n >> 5;
        int yl = slot >> 2, xg = slot & 3;
        size_t gi = gbase + (size_t)c*(HH*WW) + yl*WW + xg*4;
        float4 bv = *(const float4*)(bb + gi);
        float4 xv = *(const float4*)&tile[sgran(c, slot)*4];
        float4 ov;
        ov.x = bv.x + vf*xv.x; ov.y = bv.y + vf*xv.y;
        ov.z = bv.z + vf*xv.z; ov.w = bv.w + vf*xv.w;
        *(float4*)(out + gi) = ov;
    }
}

extern "C" void kernel_launch(void* const* d_in, const int* in_sizes, int n_in,
                              void* d_out, int out_size, void* d_ws, size_t ws_size,
                              hipStream_t stream)
{
    (void)in_sizes; (void)n_in; (void)out_size; (void)ws_size;
    const float* backbone = (const float*)d_in[0];
    const float* defe     = (const float*)d_in[1];
    const float* gpe      = (const float*)d_in[3];
    const float* rw1 = (const float*)d_in[4];
    const float* rb1 = (const float*)d_in[5];
    const float* rw2 = (const float*)d_in[6];
    const float* rb2 = (const float*)d_in[7];
    const float* ipw = (const float*)d_in[8];
    const float* ipb = (const float*)d_in[9];
    const float* opw = (const float*)d_in[10];
    const float* opb = (const float*)d_in[11];
    const float* l1w = (const float*)d_in[12];
    const float* l1b = (const float*)d_in[13];
    const float* l2w = (const float*)d_in[14];
    const float* l2b = (const float*)d_in[15];
    const float* g1  = (const float*)d_in[16];
    const float* b1  = (const float*)d_in[17];
    const float* g2  = (const float*)d_in[18];
    const float* b2  = (const float*)d_in[19];

    char* ws = (char*)d_ws;
    unsigned short* pos    = (unsigned short*)(ws);               //   8,388,608
    unsigned short* x      = (unsigned short*)(ws +   8388608);   //  33,554,432
    unsigned short* qkv    = (unsigned short*)(ws +  41943040);   // 100,663,296 (src = qkv)
    unsigned short* shared_= (unsigned short*)(ws + 142606336);   //  33,554,432 (xp -> attn)
    float*          validf = (float*)(ws + 176160768);            //       1,024
    unsigned short* ipw16  = (unsigned short*)(ws + 176161792);
    unsigned short* opw16  = (unsigned short*)(ws + 176555008);
    unsigned short* l1w16  = (unsigned short*)(ws + 176686080);
    unsigned short* l2w16  = (unsigned short*)(ws + 177210368);
    float*          rel    = (float*)(ws + 177734656);
    unsigned short* src = qkv;
    float* outf = (float*)d_out;

    wcvt_kernel<<<192, 256, 0, stream>>>(ipw, ipw16, 49152);
    wcvt_kernel<<< 64, 256, 0, stream>>>(opw, opw16, 16384);
    wcvt_kernel<<<256, 256, 0, stream>>>(l1w, l1w16, 65536);
    wcvt_kernel<<<256, 256, 0, stream>>>(l2w, l2w16, 65536);
    rel_kernel<<<256, 256, 0, stream>>>(rw1, rb1, rw2, rb2, rel);
    posT_kernel<<<512, 256, 0, stream>>>(gpe, rel, pos);
    valid_kernel<<<BB*NW, 256, 0, stream>>>(defe, validf, outf + (size_t)BB*CEMB*HH*WW);
    partition_kernel<<<2048, 256, 0, stream>>>(backbone, x);

    for (int layer = 0; layer < 2; ++layer){
        addpos_kernel<<<8192, 256, 0, stream>>>(x, pos, shared_);
        gemm_mfma<<<dim3(512, 6), 256, 0, stream>>>(shared_, x, 512, CEMB, ipw16, CEMB, ipb, qkv, 768, 0);
        if (layer == 0)
            attn_mfma<256, false><<<dim3(BB*NW, NHEAD), 256, 0, stream>>>(qkv, shared_, validf);
        else
            attn_mfma<64, true><<<dim3(BB*TT, NHEAD), 256, 0, stream>>>(qkv, shared_, validf);
        gemm_ln<<<dim3(1024, 1), 256, 0, stream>>>(shared_, CEMB, opw16, opb, x, g1, b1, src);
        ffn_fused<<<1024, 256, 0, stream>>>(src, l1w16, l1b, l2w16, l2b, g2, b2, x);
    }
    scatter_kernel<<<2048, 256, 0, stream>>>(backbone, x, validf, outf);
}

// Round 6
// 674.216 us; speedup vs baseline: 1.3373x; 1.1877x over previous
//
#include <hip/hip_runtime.h>
#include <hip/hip_bf16.h>

// ---------------- problem constants ----------------
#define CEMB 256
#define NHEAD 8
#define DHEAD 32
#define DFF 1024
#define BB 4
#define HH 128
#define WW 128
#define WSZ 16
#define NWH 8
#define NW 64
#define TT 256            // tokens per window
#define NTOK (BB*NW*TT)   // 65536

typedef __attribute__((ext_vector_type(8))) short bf16x8;
typedef __attribute__((ext_vector_type(4))) float f32x4;

// bf16 helpers (storage type = ushort)
__device__ __forceinline__ float bf2f(unsigned short u){
    union { float f; unsigned int i; } v; v.i = ((unsigned int)u) << 16; return v.f;
}
__device__ __forceinline__ unsigned short f2bf(float f){
    union { float f; unsigned int i; } v; v.f = f;
    unsigned int r = v.i + 0x7fffu + ((v.i >> 16) & 1u);
    return (unsigned short)(r >> 16);
}
__device__ __forceinline__ unsigned int cvtpk_bf16(float lo, float hi){
    unsigned int r;
    asm("v_cvt_pk_bf16_f32 %0, %1, %2" : "=v"(r) : "v"(lo), "v"(hi));
    return r;
}
__device__ __forceinline__ void unpack8(uint4 v, float* f){
    f[0]=bf2f((unsigned short)(v.x & 0xffff)); f[1]=bf2f((unsigned short)(v.x>>16));
    f[2]=bf2f((unsigned short)(v.y & 0xffff)); f[3]=bf2f((unsigned short)(v.y>>16));
    f[4]=bf2f((unsigned short)(v.z & 0xffff)); f[5]=bf2f((unsigned short)(v.z>>16));
    f[6]=bf2f((unsigned short)(v.w & 0xffff)); f[7]=bf2f((unsigned short)(v.w>>16));
}
__device__ __forceinline__ void async_copy16(const void* g, void* l){
    __builtin_amdgcn_global_load_lds(
        (const __attribute__((address_space(1))) unsigned int*)g,
        (__attribute__((address_space(3))) unsigned int*)l, 16, 0, 0);
}
// xor-swizzled LDS granule index for 64c x 128t fp32 transpose tiles
// (granule = 4 floats along t; phys granule = c*32 + (g ^ (c&31)))
__device__ __forceinline__ int sgran(int c, int g){ return c*32 + (g ^ (c & 31)); }

// ---------------- rel MLP: rel[t][c] fp32 (once) ----------------
__global__ __launch_bounds__(256) void rel_kernel(const float* __restrict__ rw1,
    const float* __restrict__ rb1, const float* __restrict__ rw2,
    const float* __restrict__ rb2, float* __restrict__ rel)
{
    __shared__ float hsh[64];
    int t = blockIdx.x, c = threadIdx.x;
    int ty = t >> 4, tx = t & 15;
    if (c < 64){
        float y = ty*(1.0f/15.0f), xx = tx*(1.0f/15.0f);
        hsh[c] = fmaxf(y*rw1[2*c] + xx*rw1[2*c+1] + rb1[c], 0.0f);
    }
    __syncthreads();
    float acc = rb2[c];
    #pragma unroll 16
    for (int k = 0; k < 64; ++k) acc += hsh[k]*rw2[c*64 + k];
    rel[t*256 + c] = acc;
}

// ---------------- pos[w][t][c] = gp^T + rel  (vectorized swizzled transpose) ----------------
// grid: 64 w * 4 cq * 2 th = 512 blocks; 64 c x 128 t tile per block
__global__ __launch_bounds__(256) void posT_kernel(const float* __restrict__ gp,
    const float* __restrict__ rel, unsigned short* __restrict__ pos)
{
    __shared__ float tile[8192];
    const int w  = blockIdx.x >> 3;
    const int cq = (blockIdx.x >> 1) & 3, th = blockIdx.x & 1;
    const int c0 = cq << 6, t0 = th << 7, y0 = th << 3;
    const int wh = w >> 3, wwi = w & 7;
    const int tid = threadIdx.x;
    const float* gpb = gp + (size_t)c0*(HH*WW) + (size_t)(wh*16 + y0)*WW + wwi*16;
    #pragma unroll
    for (int i = 0; i < 8; ++i){
        int n = i*256 + tid, slot = n & 31, c = n >> 5;
        int yl = slot >> 2, xg = slot & 3;
        float4 v = *(const float4*)(gpb + (size_t)c*(HH*WW) + yl*WW + xg*4);
        *(float4*)&tile[sgran(c, slot)*4] = v;
    }
    __syncthreads();
    #pragma unroll
    for (int i = 0; i < 4; ++i){
        int n = i*256 + tid, j = n & 7, tl = n >> 3;
        int g = tl >> 2, e = tl & 3;
        const float* rl = rel + (t0 + tl)*256 + c0 + j*8;
        unsigned short o[8];
        #pragma unroll
        for (int m = 0; m < 8; ++m)
            o[m] = f2bf(tile[sgran(j*8 + m, g)*4 + e] + rl[m]);
        *(uint4*)&pos[((size_t)w*256 + t0 + tl)*CEMB + c0 + j*8] = *(uint4*)o;
    }
}

// ---------------- K2: window validity (max-pool > 0) ----------------
__global__ __launch_bounds__(256) void valid_kernel(const float* __restrict__ defe,
    float* __restrict__ validf, float* __restrict__ tail)
{
    __shared__ float red[4];
    int bw = blockIdx.x; int b = bw >> 6, w = bw & 63;
    int t = threadIdx.x; int ty = t >> 4, tx = t & 15;
    int wh = w >> 3, wwi = w & 7;
    float v = defe[(size_t)b*(HH*WW) + (wh*16+ty)*WW + wwi*16 + tx];
    int lane = t & 63, wave = t >> 6;
    for (int off = 1; off < 64; off <<= 1) v = fmaxf(v, __shfl_xor(v, off));
    if (lane == 0) red[wave] = v;
    __syncthreads();
    if (t == 0){
        float m = fmaxf(fmaxf(red[0], red[1]), fmaxf(red[2], red[3]));
        float r = (m > 0.0f) ? 1.0f : 0.0f;
        validf[bw] = r;
        tail[bw] = r;
    }
}

// ---------------- K3: window partition  backbone[B,C,H,W] -> x[b,w,t,c] bf16 ----------------
// grid: 256 bw * 4 cq * 2 th = 2048 blocks; 64 c x 128 t tile per block
__global__ __launch_bounds__(256) void partition_kernel(const float* __restrict__ bb,
    unsigned short* __restrict__ x)
{
    __shared__ float tile[8192];
    const int bw = blockIdx.x >> 3;
    const int b = bw >> 6, w = bw & 63;
    const int cq = (blockIdx.x >> 1) & 3, th = blockIdx.x & 1;
    const int c0 = cq << 6, t0 = th << 7, y0 = th << 3;
    const int wh = w >> 3, wwi = w & 7;
    const int tid = threadIdx.x;
    const float* bbb = bb + ((size_t)(b*CEMB + c0))*(HH*WW) + (size_t)(wh*16 + y0)*WW + wwi*16;
    #pragma unroll
    for (int i = 0; i < 8; ++i){
        int n = i*256 + tid, slot = n & 31, c = n >> 5;
        int yl = slot >> 2, xg = slot & 3;
        float4 v = *(const float4*)(bbb + (size_t)c*(HH*WW) + yl*WW + xg*4);
        *(float4*)&tile[sgran(c, slot)*4] = v;
    }
    __syncthreads();
    #pragma unroll
    for (int i = 0; i < 4; ++i){
        int n = i*256 + tid, j = n & 7, tl = n >> 3;
        int g = tl >> 2, e = tl & 3;
        unsigned short o[8];
        #pragma unroll
        for (int m = 0; m < 8; ++m)
            o[m] = f2bf(tile[sgran(j*8 + m, g)*4 + e]);
        *(uint4*)&x[((size_t)bw*256 + t0 + tl)*CEMB + c0 + j*8] = *(uint4*)o;
    }
}

// ---------------- weight fp32 -> bf16 ----------------
__global__ __launch_bounds__(256) void wcvt_kernel(const float* __restrict__ w,
    unsigned short* __restrict__ o, int n4)
{
    int i = blockIdx.x*256 + threadIdx.x;
    if (i < n4){
        float4 v = ((const float4*)w)[i];
        ushort4 u;
        u.x = f2bf(v.x); u.y = f2bf(v.y); u.z = f2bf(v.z); u.w = f2bf(v.w);
        ((ushort4*)o)[i] = u;
    }
}

// ---------------- weight reshuffle: W1 -> fragment-ordered w1r (bf16) ----------------
// w1r granule n = ((c*4 + wave)*8 + kf)*64 + lane holds
// w1[c*64 + wave*16 + (lane&15)][kf*32 + (lane>>4)*8 .. +8]  (fused fp32->bf16)
__global__ __launch_bounds__(256) void wshuf1_kernel(const float* __restrict__ w,
    unsigned short* __restrict__ o)
{
    int n = blockIdx.x*256 + threadIdx.x;          // 0..32767
    int l = n & 63, kf = (n >> 6) & 7, wv = (n >> 9) & 3, c = n >> 11;
    int row = c*64 + wv*16 + (l & 15), col = kf*32 + (l >> 4)*8;
    const float* s = w + (size_t)row*256 + col;
    unsigned short u[8];
    #pragma unroll
    for (int e = 0; e < 8; ++e) u[e] = f2bf(s[e]);
    *(uint4*)&o[(size_t)n*8] = *(uint4*)u;
}

// ---------------- weight reshuffle: W2 -> fragment-ordered w2r (bf16) ----------------
// w2r granule n = (((c*2 + kk)*4 + wave)*4 + nd)*64 + lane holds
// w2[wave*64 + nd*16 + (lane&15)][c*64 + kk*32 + (lane>>4)*8 .. +8]
__global__ __launch_bounds__(256) void wshuf2_kernel(const float* __restrict__ w,
    unsigned short* __restrict__ o)
{
    int n = blockIdx.x*256 + threadIdx.x;          // 0..32767
    int l = n & 63, nd = (n >> 6) & 3, wv = (n >> 8) & 3, kk = (n >> 10) & 1, c = n >> 11;
    int row = wv*64 + nd*16 + (l & 15), col = c*64 + kk*32 + (l >> 4)*8;
    const float* s = w + (size_t)row*1024 + col;
    unsigned short u[8];
    #pragma unroll
    for (int e = 0; e < 8; ++e) u[e] = f2bf(s[e]);
    *(uint4*)&o[(size_t)n*8] = *(uint4*)u;
}

// ---------------- xp = x + pos (bf16 elementwise, 8 el/thread) ----------------
__global__ __launch_bounds__(256) void addpos_kernel(const unsigned short* __restrict__ x,
    const unsigned short* __restrict__ pos, unsigned short* __restrict__ xp)
{
    size_t i = ((size_t)blockIdx.x*256 + threadIdx.x) * 8;
    size_t tok = i >> 8; int c = (int)(i & 255);
    size_t pi = ((tok & 16383) << 8) + c;
    uint4 xv = *(const uint4*)&x[i];
    uint4 pv = *(const uint4*)&pos[pi];
    float xf[8], pf[8]; unpack8(xv, xf); unpack8(pv, pf);
    unsigned short o[8];
    #pragma unroll
    for (int j = 0; j < 8; ++j) o[j] = f2bf(xf[j] + pf[j]);
    *(uint4*)&xp[i] = *(uint4*)o;
}

// ---------------- MFMA GEMM: out[M,N](bf16) = A[M,K](bf16) @ W[N,K]^T + bias ----------------
// K-tile LDS layout is XOR-swizzled at 16B granule: phys granule (r, g) holds
// logical granule (r, g ^ ((r>>1)&3)).  global_load_lds writes linearly, so the
// swizzle is applied by pre-swizzling the *source* offset; reads XOR the granule.
__global__ __launch_bounds__(256) void gemm_mfma(
    const unsigned short* __restrict__ A,
    const unsigned short* __restrict__ A2, int nsplit, int ldA,
    const unsigned short* __restrict__ W, int K,
    const float* __restrict__ bias,
    unsigned short* __restrict__ out, int ldO, int relu)
{
    __shared__ unsigned short As[128*32];
    __shared__ unsigned short Bs[128*32];
    const int m0 = blockIdx.x << 7, n0 = blockIdx.y << 7;
    const int tid = threadIdx.x;
    const int lane = tid & 63, wave = tid >> 6;
    const int wm = wave & 1, wn = wave >> 1;
    const int fl = lane & 15, quad = lane >> 4;

    const unsigned short* Ap = ((n0 < nsplit) ? A : A2) + (size_t)m0*ldA;
    const unsigned short* Wp = W + (size_t)n0*K;

    const int c0 = tid, c1 = tid + 256;
    const int r0 = c0 >> 2, o0 = ((c0 & 3) ^ ((c0 >> 3) & 3)) << 3;
    const int r1 = c1 >> 2, o1 = ((c1 & 3) ^ ((c1 >> 3) & 3)) << 3;
    // read-side swizzle: row bits 1..2 == fl bits 1..2 (i*16, wm*64 don't touch them)
    const int sw = (quad ^ ((fl >> 1) & 3)) << 3;

    f32x4 acc[4][4] = {};

    for (int k0 = 0; k0 < K; k0 += 32){
        async_copy16(Ap + (size_t)r0*ldA + k0 + o0, &As[c0 << 3]);
        async_copy16(Ap + (size_t)r1*ldA + k0 + o1, &As[c1 << 3]);
        async_copy16(Wp + (size_t)r0*K   + k0 + o0, &Bs[c0 << 3]);
        async_copy16(Wp + (size_t)r1*K   + k0 + o1, &Bs[c1 << 3]);
        __syncthreads();
        bf16x8 av[4], bv[4];
        #pragma unroll
        for (int i = 0; i < 4; ++i){
            av[i] = *(const bf16x8*)&As[(wm*64 + i*16 + fl)*32 + sw];
            bv[i] = *(const bf16x8*)&Bs[(wn*64 + i*16 + fl)*32 + sw];
        }
        #pragma unroll
        for (int i = 0; i < 4; ++i)
            #pragma unroll
            for (int j = 0; j < 4; ++j)
                acc[i][j] = __builtin_amdgcn_mfma_f32_16x16x32_bf16(av[i], bv[j], acc[i][j], 0, 0, 0);
        __syncthreads();
    }

    float bj[4];
    #pragma unroll
    for (int j = 0; j < 4; ++j) bj[j] = bias[n0 + wn*64 + j*16 + fl];
    #pragma unroll
    for (int i = 0; i < 4; ++i){
        int mrow = m0 + wm*64 + i*16 + quad*4;
        #pragma unroll
        for (int j = 0; j < 4; ++j){
            int col = n0 + wn*64 + j*16 + fl;
            #pragma unroll
            for (int r = 0; r < 4; ++r){
                float v = acc[i][j][r] + bj[j];
                if (relu) v = fmaxf(v, 0.0f);
                out[(size_t)(mrow + r)*ldO + col] = f2bf(v);
            }
        }
    }
}

// ---------------- MFMA GEMM + residual + LayerNorm (N == 256 exactly) ----------------
// 64-row tile, 4 waves each owning a 64x64 quadrant of columns: acc = 64 f32/lane
__global__ __launch_bounds__(256, 3) void gemm_ln(
    const unsigned short* __restrict__ A, int K,
    const unsigned short* __restrict__ W,
    const float* __restrict__ bias,
    const unsigned short* __restrict__ resid,
    const float* __restrict__ g, const float* __restrict__ b,
    unsigned short* __restrict__ out)
{
    __shared__ unsigned short As[64*32];
    __shared__ unsigned short Bs[256*32];
    __shared__ float psum[4][64];
    __shared__ float psq[4][64];
    const int m0 = blockIdx.x << 6;
    const int tid = threadIdx.x, lane = tid & 63, wave = tid >> 6;
    const int wn = wave;
    const int fl = lane & 15, quad = lane >> 4;

    const unsigned short* Ap = A + (size_t)m0*K;

    const int ra = tid >> 2, oa = ((tid & 3) ^ ((tid >> 3) & 3)) << 3;
    const int sw = (quad ^ ((fl >> 1) & 3)) << 3;

    f32x4 acc[4][4] = {};

    for (int k0 = 0; k0 < K; k0 += 32){
        async_copy16(Ap + (size_t)ra*K + k0 + oa, &As[tid << 3]);
        #pragma unroll
        for (int t = 0; t < 4; ++t){
            int c = tid + t*256;
            int r = c >> 2, o = ((c & 3) ^ ((c >> 3) & 3)) << 3;
            async_copy16(W + (size_t)r*K + k0 + o, &Bs[c << 3]);
        }
        __syncthreads();
        bf16x8 av[4], bv[4];
        #pragma unroll
        for (int i = 0; i < 4; ++i)
            av[i] = *(const bf16x8*)&As[(i*16 + fl)*32 + sw];
        #pragma unroll
        for (int j = 0; j < 4; ++j)
            bv[j] = *(const bf16x8*)&Bs[(wn*64 + j*16 + fl)*32 + sw];
        #pragma unroll
        for (int i = 0; i < 4; ++i)
            #pragma unroll
            for (int j = 0; j < 4; ++j)
                acc[i][j] = __builtin_amdgcn_mfma_f32_16x16x32_bf16(av[i], bv[j], acc[i][j], 0, 0, 0);
        __syncthreads();
    }

    float bcol[4], gcol[4], bbcol[4];
    #pragma unroll
    for (int j = 0; j < 4; ++j){
        int col = wn*64 + j*16 + fl;
        bcol[j] = bias[col]; gcol[j] = g[col]; bbcol[j] = b[col];
    }
    float s[4][4] = {{0}}, sq[4][4] = {{0}};
    #pragma unroll
    for (int i = 0; i < 4; ++i)
        #pragma unroll
        for (int r = 0; r < 4; ++r){
            int row = m0 + i*16 + quad*4 + r;
            #pragma unroll
            for (int j = 0; j < 4; ++j){
                float h = acc[i][j][r] + bcol[j]
                        + bf2f(resid[(size_t)row*256 + wn*64 + j*16 + fl]);
                acc[i][j][r] = h;
                s[i][r] += h; sq[i][r] += h*h;
            }
        }
    #pragma unroll
    for (int i = 0; i < 4; ++i)
        #pragma unroll
        for (int r = 0; r < 4; ++r){
            float ss = s[i][r], qq = sq[i][r];
            ss += __shfl_xor(ss, 1); qq += __shfl_xor(qq, 1);
            ss += __shfl_xor(ss, 2); qq += __shfl_xor(qq, 2);
            ss += __shfl_xor(ss, 4); qq += __shfl_xor(qq, 4);
            ss += __shfl_xor(ss, 8); qq += __shfl_xor(qq, 8);
            if (fl == 0){
                int lr = i*16 + quad*4 + r;
                psum[wn][lr] = ss; psq[wn][lr] = qq;
            }
        }
    __syncthreads();
    #pragma unroll
    for (int i = 0; i < 4; ++i)
        #pragma unroll
        for (int r = 0; r < 4; ++r){
            int lr = i*16 + quad*4 + r;
            float mu  = (psum[0][lr] + psum[1][lr] + psum[2][lr] + psum[3][lr]) * (1.0f/256.0f);
            float var = (psq[0][lr] + psq[1][lr] + psq[2][lr] + psq[3][lr]) * (1.0f/256.0f) - mu*mu;
            float rstd = rsqrtf(var + 1e-5f);
            #pragma unroll
            for (int j = 0; j < 4; ++j){
                int col = wn*64 + j*16 + fl;
                out[(size_t)(m0 + lr)*256 + col] =
                    f2bf((acc[i][j][r] - mu)*rstd*gcol[j] + bbcol[j]);
            }
        }
}

// ---------------- fused FFN v3: out = LN2( src + relu(src@W1^T+b1)@W2^T + b2 ) ----------------
// 64-row block, 4 waves, 16 hid-chunks of 64. Weights come from the
// fragment-ordered w1r/w2r layouts (wshuf kernels): each fragment load is a
// lane-contiguous coalesced global_load_dwordx4 into registers — no weight LDS,
// no global_load_lds in the loop. Register double-buffer: w1f(c+1)/w2f(c+1)
// are issued in source order right after chunk c consumes them, giving a full
// chunk of HBM/L2 latency hiding; the compiler emits counted vmcnt waits.
// The two hlds-handoff barriers are RAW s_barrier + lgkmcnt(0) (only LDS
// crosses them) so prefetched weight loads stay in flight across barriers
// (a __syncthreads vmcnt(0) drain here would re-expose the latency — R5's bug).
// src is staged once into swizzled LDS (32KB): qf reads + residual come from
// LDS, so src is read from global exactly once per block.
__global__ __launch_bounds__(256, 2) void ffn_fused(
    const unsigned short* __restrict__ src,
    const unsigned short* __restrict__ w1r,  // fragment-ordered [16][4][8][64] granules
    const float* __restrict__ b1,
    const unsigned short* __restrict__ w2r,  // fragment-ordered [16][2][4][4][64] granules
    const float* __restrict__ b2,
    const float* __restrict__ g, const float* __restrict__ b,
    unsigned short* __restrict__ out)
{
    __shared__ unsigned short slds[64*256];  // 32KB src tile, granule-swizzled
    __shared__ unsigned short hlds[64*64];   // 8KB h tile
    __shared__ float psum[4][64];
    __shared__ float psq[4][64];
    const int m0 = blockIdx.x << 6;
    const int tid = threadIdx.x, lane = tid & 63, wave = tid >> 6;
    const int fl = lane & 15, quad = lane >> 4;
    const int fsl = fl & 7;

    // stage src once: phys granule (row, gp) holds logical granule gp^(row&7)
    #pragma unroll
    for (int i = 0; i < 8; ++i){
        int G = i*256 + tid, row = G >> 5, gp = G & 31;
        async_copy16(src + (size_t)(m0 + row)*256 + ((gp ^ (row & 7)) << 3), &slds[G << 3]);
    }
    asm volatile("s_waitcnt vmcnt(0)" ::: "memory");
    __builtin_amdgcn_sched_barrier(0);
    __builtin_amdgcn_s_barrier();

    f32x4 acc[4][4] = {};
    const int gwr = wave*2 + (quad >> 1);    // write-side h granule
    const int who = (quad & 1) << 2;         // within-granule ushort offset

    // prologue: weight fragments for chunk 0
    bf16x8 w1f[8], w2f[2][4];
    #pragma unroll
    for (int kf = 0; kf < 8; ++kf)
        w1f[kf] = *(const bf16x8*)&w1r[(size_t)((wave*8 + kf)*64 + lane)*8];
    #pragma unroll
    for (int kk = 0; kk < 2; ++kk)
        #pragma unroll
        for (int nd = 0; nd < 4; ++nd)
            w2f[kk][nd] = *(const bf16x8*)&w2r[(size_t)(((kk*4 + wave)*4 + nd)*64 + lane)*8];

    #pragma unroll 1
    for (int c = 0; c < 16; ++c){
        const int j0 = c << 6;
        float4 b1v = *(const float4*)&b1[j0 + wave*16 + quad*4];
        // ---- GEMM1: h^T[16 hid (this wave)][64 rows] = W1c . src^T ----
        #pragma unroll
        for (int mi = 0; mi < 4; ++mi){
            bf16x8 qf[8];
            #pragma unroll
            for (int kf = 0; kf < 8; ++kf)
                qf[kf] = *(const bf16x8*)&slds[((mi*16 + fl)*32 + ((kf*4 + quad) ^ fsl)) << 3];
            f32x4 sacc = {};
            #pragma unroll
            for (int kf = 0; kf < 8; ++kf)
                sacc = __builtin_amdgcn_mfma_f32_16x16x32_bf16(w1f[kf], qf[kf], sacc, 0, 0, 0);
            float h0 = fmaxf(sacc[0] + b1v.x, 0.0f);
            float h1 = fmaxf(sacc[1] + b1v.y, 0.0f);
            float h2 = fmaxf(sacc[2] + b1v.z, 0.0f);
            float h3 = fmaxf(sacc[3] + b1v.w, 0.0f);
            int r_ = mi*16 + fl;
            int gb = r_*64 + ((gwr ^ fsl) << 3) + who;
            *(unsigned int*)&hlds[gb    ] = cvtpk_bf16(h0, h1);
            *(unsigned int*)&hlds[gb + 2] = cvtpk_bf16(h2, h3);
        }
        // prefetch W1(c+1) fragments (registers; consumed next chunk)
        if (c < 15){
            #pragma unroll
            for (int kf = 0; kf < 8; ++kf)
                w1f[kf] = *(const bf16x8*)&w1r[(size_t)((((c+1)*4 + wave)*8 + kf)*64 + lane)*8];
        }
        asm volatile("s_waitcnt lgkmcnt(0)" ::: "memory");
        __builtin_amdgcn_sched_barrier(0);
        __builtin_amdgcn_s_barrier();      // hlds ready (raw: weight loads stay in flight)
        __builtin_amdgcn_sched_barrier(0);
        // ---- GEMM2: acc += h . W2c^T ----
        #pragma unroll
        for (int kk = 0; kk < 2; ++kk){
            bf16x8 hf[4];
            #pragma unroll
            for (int mi = 0; mi < 4; ++mi)
                hf[mi] = *(const bf16x8*)&hlds[(mi*16 + fl)*64 + (((kk*4 + quad) ^ fsl) << 3)];
            #pragma unroll
            for (int mi = 0; mi < 4; ++mi)
                #pragma unroll
                for (int nd = 0; nd < 4; ++nd)
                    acc[mi][nd] = __builtin_amdgcn_mfma_f32_16x16x32_bf16(hf[mi], w2f[kk][nd], acc[mi][nd], 0, 0, 0);
        }
        // prefetch W2(c+1) fragments
        if (c < 15){
            #pragma unroll
            for (int kk = 0; kk < 2; ++kk)
                #pragma unroll
                for (int nd = 0; nd < 4; ++nd)
                    w2f[kk][nd] = *(const bf16x8*)&w2r[(size_t)(((((c+1)*2 + kk)*4 + wave)*4 + nd)*64 + lane)*8];
        }
        asm volatile("s_waitcnt lgkmcnt(0)" ::: "memory");
        __builtin_amdgcn_sched_barrier(0);
        __builtin_amdgcn_s_barrier();      // hlds reads done; next chunk may overwrite
        __builtin_amdgcn_sched_barrier(0);
    }

    // ---- epilogue: + b2 + resid(slds), LayerNorm(g,b) -> out ----
    float bcol[4], gcol[4], bbcol[4];
    #pragma unroll
    for (int j = 0; j < 4; ++j){
        int col = wave*64 + j*16 + fl;
        bcol[j] = b2[col]; gcol[j] = g[col]; bbcol[j] = b[col];
    }
    float s[4][4] = {{0}}, sq[4][4] = {{0}};
    #pragma unroll
    for (int i = 0; i < 4; ++i)
        #pragma unroll
        for (int r = 0; r < 4; ++r){
            int lr = i*16 + quad*4 + r;
            #pragma unroll
            for (int j = 0; j < 4; ++j){
                int gcol2 = wave*8 + j*2 + (fl >> 3);
                float rv = bf2f(slds[((lr*32 + (gcol2 ^ (lr & 7))) << 3) + (fl & 7)]);
                float h = acc[i][j][r] + bcol[j] + rv;
                acc[i][j][r] = h;
                s[i][r] += h; sq[i][r] += h*h;
            }
        }
    #pragma unroll
    for (int i = 0; i < 4; ++i)
        #pragma unroll
        for (int r = 0; r < 4; ++r){
            float ss = s[i][r], qq = sq[i][r];
            ss += __shfl_xor(ss, 1); qq += __shfl_xor(qq, 1);
            ss += __shfl_xor(ss, 2); qq += __shfl_xor(qq, 2);
            ss += __shfl_xor(ss, 4); qq += __shfl_xor(qq, 4);
            ss += __shfl_xor(ss, 8); qq += __shfl_xor(qq, 8);
            if (fl == 0){
                int lr = i*16 + quad*4 + r;
                psum[wave][lr] = ss; psq[wave][lr] = qq;
            }
        }
    __syncthreads();
    #pragma unroll
    for (int i = 0; i < 4; ++i)
        #pragma unroll
        for (int r = 0; r < 4; ++r){
            int lr = i*16 + quad*4 + r;
            float mu  = (psum[0][lr] + psum[1][lr] + psum[2][lr] + psum[3][lr]) * (1.0f/256.0f);
            float var = (psq[0][lr] + psq[1][lr] + psq[2][lr] + psq[3][lr]) * (1.0f/256.0f) - mu*mu;
            float rstd = rsqrtf(var + 1e-5f);
            #pragma unroll
            for (int j = 0; j < 4; ++j){
                int col = wave*64 + j*16 + fl;
                out[(size_t)(m0 + lr)*256 + col] =
                    f2bf((acc[i][j][r] - mu)*rstd*gcol[j] + bbcol[j]);
            }
        }
}

// ---------------- MFMA flash attention (in-register P via swapped QK^T) ----------------
// S^T = mfma(K, Q): lane holds S[k = nj*16+quad*4+r][q = mi*16+fl].
// P is packed to bf16 in-register (v_cvt_pk_bf16_f32) and redistributed to the
// PV A-fragment layout (k = quad*8+j) with a fixed cross-quad shfl exchange —
// no P LDS round-trip, no Ps buffer.
template<int L, bool CROSS>
__global__ __launch_bounds__(256, 3) void attn_mfma(const unsigned short* __restrict__ qkv,
    unsigned short* __restrict__ attn_out, const float* __restrict__ validf)
{
    constexpr int QW  = (L == 256) ? 64 : 16;
    constexpr int MI  = QW / 16;
    constexpr int VTS = L + 8;
    constexpr int LOG = (L == 256) ? 8 : 6;
    __shared__ unsigned short Ks[L*32];
    __shared__ unsigned short Vt[32*VTS];

    const int s = blockIdx.x, h = blockIdx.y;
    int base, stride;
    if (CROSS){ base = (s >> 8)*16384 + (s & 255); stride = 256; }
    else      { base = s << 8; stride = 1; }
    const int tid = threadIdx.x, lane = tid & 63, wave = tid >> 6;
    const int fl = lane & 15, quad = lane >> 4;
    const float scale = 0.17677669529663687f;

    // K staging, XOR-swizzled at 16B granule (source pre-swizzle, rule 21)
    for (int cid = tid; cid < L*4; cid += 256){
        int j = cid >> 2, part = (cid & 3) ^ ((cid >> 3) & 3);
        async_copy16(qkv + (size_t)(base + j*stride)*768 + 256 + h*32 + part*8, &Ks[cid*8]);
    }
    for (int e = tid; e < L*4; e += 256){
        int j = e & (L-1), dp = e >> LOG;
        uint4 vv = *(const uint4*)(qkv + (size_t)(base + j*stride)*768 + 512 + h*32 + dp*8);
        unsigned short tmp[8]; *(uint4*)tmp = vv;
        #pragma unroll
        for (int d = 0; d < 8; ++d) Vt[(dp*8 + d)*VTS + j] = tmp[d];
    }
    __syncthreads();

    bf16x8 qf[MI];
    #pragma unroll
    for (int mi = 0; mi < MI; ++mi){
        int q = wave*QW + mi*16 + fl;
        qf[mi] = *(const bf16x8*)(qkv + (size_t)(base + q*stride)*768 + h*32 + quad*8);
    }
    float vm[4][4];
    if (CROSS){
        #pragma unroll
        for (int nj = 0; nj < 4; ++nj){
            float4 v4 = *(const float4*)&validf[(s >> 8)*64 + nj*16 + quad*4];
            vm[nj][0] = v4.x; vm[nj][1] = v4.y; vm[nj][2] = v4.z; vm[nj][3] = v4.w;
        }
    }

    f32x4 oacc[MI][2] = {};
    float lpart[MI] = {};
    const int sw = (quad ^ ((fl >> 1) & 3)) << 3;
    const int la = fl | ((quad & 1) << 5);   // src lane, quads {0,2}
    const int lb = la + 16;                  // src lane, quads {1,3}

    for (int j0 = 0; j0 < L; j0 += 64){
        bf16x8 kf[4];
        #pragma unroll
        for (int nj = 0; nj < 4; ++nj)
            kf[nj] = *(const bf16x8*)&Ks[(j0 + nj*16 + fl)*32 + sw];
        unsigned int pk[MI][4][2];
        #pragma unroll
        for (int mi = 0; mi < MI; ++mi){
            f32x4 sacc[4] = {};
            #pragma unroll
            for (int nj = 0; nj < 4; ++nj)
                sacc[nj] = __builtin_amdgcn_mfma_f32_16x16x32_bf16(kf[nj], qf[mi], sacc[nj], 0, 0, 0);
            #pragma unroll
            for (int nj = 0; nj < 4; ++nj){
                float p[4];
                #pragma unroll
                for (int r = 0; r < 4; ++r){
                    float pv = __expf(sacc[nj][r] * scale);
                    if (CROSS) pv *= vm[nj][r];
                    p[r] = pv;
                    lpart[mi] += pv;
                }
                pk[mi][nj][0] = cvtpk_bf16(p[0], p[1]);
                pk[mi][nj][1] = cvtpk_bf16(p[2], p[3]);
            }
        }
        #pragma unroll
        for (int kk = 0; kk < 2; ++kk){
            bf16x8 vf[2];
            #pragma unroll
            for (int nd = 0; nd < 2; ++nd)
                vf[nd] = *(const bf16x8*)&Vt[(nd*16 + fl)*VTS + j0 + kk*32 + quad*8];
            #pragma unroll
            for (int mi = 0; mi < MI; ++mi){
                unsigned int a0 = __shfl(pk[mi][2*kk  ][0], la, 64);
                unsigned int a1 = __shfl(pk[mi][2*kk  ][1], la, 64);
                unsigned int a2 = __shfl(pk[mi][2*kk  ][0], lb, 64);
                unsigned int a3 = __shfl(pk[mi][2*kk  ][1], lb, 64);
                unsigned int b0 = __shfl(pk[mi][2*kk+1][0], la, 64);
                unsigned int b1 = __shfl(pk[mi][2*kk+1][1], la, 64);
                unsigned int b2 = __shfl(pk[mi][2*kk+1][0], lb, 64);
                unsigned int b3 = __shfl(pk[mi][2*kk+1][1], lb, 64);
                const bool lo = quad < 2;
                union { unsigned int u[4]; bf16x8 v; } pu;
                pu.u[0] = lo ? a0 : b0;
                pu.u[1] = lo ? a1 : b1;
                pu.u[2] = lo ? a2 : b2;
                pu.u[3] = lo ? a3 : b3;
                #pragma unroll
                for (int nd = 0; nd < 2; ++nd)
                    oacc[mi][nd] = __builtin_amdgcn_mfma_f32_16x16x32_bf16(pu.v, vf[nd], oacc[mi][nd], 0, 0, 0);
            }
        }
    }

    #pragma unroll
    for (int mi = 0; mi < MI; ++mi){
        float l = lpart[mi];
        l += __shfl_xor(l, 16);
        l += __shfl_xor(l, 32);
        l = 1.0f / l;
        float li[4];
        #pragma unroll
        for (int r = 0; r < 4; ++r)
            li[r] = __shfl(l, quad*4 + r, 64);
        #pragma unroll
        for (int nd = 0; nd < 2; ++nd)
            #pragma unroll
            for (int r = 0; r < 4; ++r){
                int q = wave*QW + mi*16 + quad*4 + r;
                attn_out[(size_t)(base + q*stride)*CEMB + h*32 + nd*16 + fl] =
                    f2bf(oacc[mi][nd][r] * li[r]);
            }
    }
}

// ---------------- final scatter: out = backbone + valid * x (vectorized swizzled) ----------------
// grid: 256 bw * 4 cq * 2 th = 2048 blocks; 64 c x 128 t tile per block
__global__ __launch_bounds__(256) void scatter_kernel(const float* __restrict__ bb,
    const unsigned short* __restrict__ x, const float* __restrict__ validf,
    float* __restrict__ out)
{
    __shared__ float tile[8192];
    const int bw = blockIdx.x >> 3;
    const int b = bw >> 6, w = bw & 63;
    const int cq = (blockIdx.x >> 1) & 3, th = blockIdx.x & 1;
    const int c0 = cq << 6, t0 = th << 7, y0 = th << 3;
    const int wh = w >> 3, wwi = w & 7;
    const int tid = threadIdx.x;
    const float vf = validf[bw];
    // phase 1: x (t-major bf16) -> swizzled LDS (c-major fp32)
    #pragma unroll
    for (int i = 0; i < 4; ++i){
        int n = i*256 + tid, j = n & 7, tl = n >> 3;
        int g = tl >> 2, e = tl & 3;
        uint4 xv = *(const uint4*)&x[((size_t)bw*256 + t0 + tl)*CEMB + c0 + j*8];
        float f[8]; unpack8(xv, f);
        #pragma unroll
        for (int m = 0; m < 8; ++m)
            tile[sgran(j*8 + m, g)*4 + e] = f[m];
    }
    __syncthreads();
    // phase 2: out = bb + vf * tile (c-major float4)
    const size_t gbase = ((size_t)(b*CEMB + c0))*(HH*WW) + (size_t)(wh*16 + y0)*WW + wwi*16;
    #pragma unroll
    for (int i = 0; i < 8; ++i){
        int n = i*256 + tid, slot = n & 31, c = n >> 5;
        int yl = slot >> 2, xg = slot & 3;
        size_t gi = gbase + (size_t)c*(HH*WW) + yl*WW + xg*4;
        float4 bv = *(const float4*)(bb + gi);
        float4 xv = *(const float4*)&tile[sgran(c, slot)*4];
        float4 ov;
        ov.x = bv.x + vf*xv.x; ov.y = bv.y + vf*xv.y;
        ov.z = bv.z + vf*xv.z; ov.w = bv.w + vf*xv.w;
        *(float4*)(out + gi) = ov;
    }
}

extern "C" void kernel_launch(void* const* d_in, const int* in_sizes, int n_in,
                              void* d_out, int out_size, void* d_ws, size_t ws_size,
                              hipStream_t stream)
{
    (void)in_sizes; (void)n_in; (void)out_size; (void)ws_size;
    const float* backbone = (const float*)d_in[0];
    const float* defe     = (const float*)d_in[1];
    const float* gpe      = (const float*)d_in[3];
    const float* rw1 = (const float*)d_in[4];
    const float* rb1 = (const float*)d_in[5];
    const float* rw2 = (const float*)d_in[6];
    const float* rb2 = (const float*)d_in[7];
    const float* ipw = (const float*)d_in[8];
    const float* ipb = (const float*)d_in[9];
    const float* opw = (const float*)d_in[10];
    const float* opb = (const float*)d_in[11];
    const float* l1w = (const float*)d_in[12];
    const float* l1b = (const float*)d_in[13];
    const float* l2w = (const float*)d_in[14];
    const float* l2b = (const float*)d_in[15];
    const float* g1  = (const float*)d_in[16];
    const float* b1  = (const float*)d_in[17];
    const float* g2  = (const float*)d_in[18];
    const float* b2  = (const float*)d_in[19];

    char* ws = (char*)d_ws;
    unsigned short* pos    = (unsigned short*)(ws);               //   8,388,608
    unsigned short* x      = (unsigned short*)(ws +   8388608);   //  33,554,432
    unsigned short* qkv    = (unsigned short*)(ws +  41943040);   // 100,663,296 (src = qkv)
    unsigned short* shared_= (unsigned short*)(ws + 142606336);   //  33,554,432 (xp -> attn)
    float*          validf = (float*)(ws + 176160768);            //       1,024
    unsigned short* ipw16  = (unsigned short*)(ws + 176161792);
    unsigned short* opw16  = (unsigned short*)(ws + 176555008);
    unsigned short* w1r    = (unsigned short*)(ws + 176686080);   // 524,288 (reshuffled W1)
    unsigned short* w2r    = (unsigned short*)(ws + 177210368);   // 524,288 (reshuffled W2)
    float*          rel    = (float*)(ws + 177734656);
    unsigned short* src = qkv;
    float* outf = (float*)d_out;

    wcvt_kernel<<<192, 256, 0, stream>>>(ipw, ipw16, 49152);
    wcvt_kernel<<< 64, 256, 0, stream>>>(opw, opw16, 16384);
    wshuf1_kernel<<<128, 256, 0, stream>>>(l1w, w1r);
    wshuf2_kernel<<<128, 256, 0, stream>>>(l2w, w2r);
    rel_kernel<<<256, 256, 0, stream>>>(rw1, rb1, rw2, rb2, rel);
    posT_kernel<<<512, 256, 0, stream>>>(gpe, rel, pos);
    valid_kernel<<<BB*NW, 256, 0, stream>>>(defe, validf, outf + (size_t)BB*CEMB*HH*WW);
    partition_kernel<<<2048, 256, 0, stream>>>(backbone, x);

    for (int layer = 0; layer < 2; ++layer){
        addpos_kernel<<<8192, 256, 0, stream>>>(x, pos, shared_);
        gemm_mfma<<<dim3(512, 6), 256, 0, stream>>>(shared_, x, 512, CEMB, ipw16, CEMB, ipb, qkv, 768, 0);
        if (layer == 0)
            attn_mfma<256, false><<<dim3(BB*NW, NHEAD), 256, 0, stream>>>(qkv, shared_, validf);
        else
            attn_mfma<64, true><<<dim3(BB*TT, NHEAD), 256, 0, stream>>>(qkv, shared_, validf);
        gemm_ln<<<dim3(1024, 1), 256, 0, stream>>>(shared_, CEMB, opw16, opb, x, g1, b1, src);
        ffn_fused<<<1024, 256, 0, stream>>>(src, w1r, l1b, w2r, l2b, g2, b2, x);
    }
    scatter_kernel<<<2048, 256, 0, stream>>>(backbone, x, validf, outf);
}